// Round 14
// baseline (11721.093 us; speedup 1.0000x reference)
//
#include <hip/hip_runtime.h>
#include <math.h>
#include <stdint.h>

namespace {

typedef __attribute__((ext_vector_type(8))) short short8v;   // 8 bf16 = 4 VGPR
typedef __attribute__((ext_vector_type(4))) float f32x4;

constexpr int TT = 256;

// ---- ws float offsets (total 9,551,872 floats = 38.2 MB, proven) ----
constexpr size_t S_ST   = 0;          // c0T,h1T,c1T [3][64][512]
constexpr size_t S_P0   = 98304;      // [2][64][6144]
constexpr size_t S_P1   = 884736;     // [2][64][6144]
constexpr size_t S_WSP  = 1671168;    // 13,631,488 ushorts: spline weights hi/lo
constexpr size_t S_FEAT = 8486912;    // 2,129,920 ushorts: features
constexpr size_t WS_NEED = 9551872ull * 4;

// ushort offsets inside wsp (spline split weights, [8][512][W])
constexpr size_t SWT0H = 0,       SWT0L = 2621440;
constexpr size_t SWT1H = 5242880, SWT1L = 9437184;

// ---- ushort offsets within FEAT ----
constexpr size_t FZ0H = 0,       FZ0L = 40960,  FS0H = 81920,  FS0L = 122880;
constexpr size_t FB0H = 163840,  FB0L = 491520;                 // planes 64*640
constexpr size_t L1F  = 819200;
constexpr size_t FZ1H = L1F,          FZ1L = L1F + 65536;
constexpr size_t FS1H = L1F + 131072, FS1L = L1F + 196608;
constexpr size_t FB1H = L1F + 262144, FB1L = L1F + 786432;      // planes 64*1024

__device__ __forceinline__ float sigmoidf_(float v) { return 1.0f / (1.0f + expf(-v)); }

__device__ __forceinline__ ushort bf16h(float v) {          // RNE f32 -> bf16 bits
    uint32_t u = __float_as_uint(v);
    return (ushort)((u + 0x7fffu + ((u >> 16) & 1u)) >> 16);
}
__device__ __forceinline__ float bf16f(ushort h) { return __uint_as_float(((uint32_t)h) << 16); }
__device__ __forceinline__ void put2(ushort* hi, ushort* lo, size_t idx, float v) {
    ushort h = bf16h(v); hi[idx] = h; lo[idx] = bf16h(v - bf16f(h));
}

// Cox-de Boor, GRID_SIZE=5, ORDER=3 (verified rounds 7-13)
__device__ __forceinline__ void bspline8(float x, float* out) {
    const float KG[12] = {-2.2f,-1.8f,-1.4f,-1.0f,-0.6f,-0.2f,
                           0.2f, 0.6f, 1.0f, 1.4f, 1.8f, 2.2f};
    float b[11];
#pragma unroll
    for (int i = 0; i < 11; ++i)
        b[i] = (x >= KG[i] && x < KG[i + 1]) ? 1.0f : 0.0f;
#pragma unroll
    for (int p = 1; p <= 3; ++p) {
#pragma unroll
        for (int i = 0; i + p < 11; ++i) {
            float l = (x - KG[i])         * (1.0f / (KG[i + p] - KG[i]));
            float r = (KG[i + p + 1] - x) * (1.0f / (KG[i + p + 1] - KG[i + 1]));
            b[i] = l * b[i] + r * b[i + 1];
        }
    }
#pragma unroll
    for (int i = 0; i < 8; ++i) out[i] = b[i];
}

__device__ __forceinline__ void write_featsT(float z, ushort* fe,
        size_t zh, size_t zl, size_t sh, size_t sl, size_t bh, size_t bl,
        size_t pstride, size_t idx)
{
    put2(fe + zh, fe + zl, idx, z);
    put2(fe + sh, fe + sl, idx, z / (1.0f + expf(-z)));
    float bs[8];
    bspline8(z, bs);
#pragma unroll
    for (int r = 0; r < 8; ++r)
        put2(fe + bh + (size_t)r * pstride, fe + bl + (size_t)r * pstride, idx, bs[r]);
}

__global__ __launch_bounds__(256) void sentinel_kernel(float* out, float v) {
    int i = blockIdx.x * 256 + threadIdx.x;
    if (i < 8192) out[i] = v;
}

// states zero + t=0 x-features + zero-state hidden features for both layers
__global__ __launch_bounds__(256) void prologue_kernel(
    const float* __restrict__ x, float* __restrict__ st, ushort* __restrict__ fe)
{
    const int g = blockIdx.x * 256 + threadIdx.x;    // 672*256 = 172032
    if (g < 98304) {
        st[g] = 0.0f;                                // c0T,h1T,c1T
    } else if (g < 106496) {                         // t=0 x feats (k<128)
        const int i = g - 98304, k = i & 127, b = i >> 7;
        write_featsT(x[((size_t)b * TT) * 128 + k], fe,
                     FZ0H, FZ0L, FS0H, FS0L, FB0H, FB0L, 40960, (size_t)b * 640 + k);
    } else if (g < 139264) {                         // L0 hidden feats h0(-1)=0
        const int i = g - 106496, o = i & 511, b = i >> 9;
        write_featsT(0.0f, fe, FZ0H, FZ0L, FS0H, FS0L, FB0H, FB0L,
                     40960, (size_t)b * 640 + 128 + o);
    } else {                                         // L1 hidden feats h1(-1)=0
        const int i = g - 139264, o = i & 511, b = i >> 9;
        write_featsT(0.0f, fe, FZ1H, FZ1L, FS1H, FS1L, FB1H, FB1L,
                     65536, (size_t)b * 1024 + 512 + o);
    }
}

// ksp [512][W][8] fp32 -> hi/lo bf16 [8][512][W]  (values identical to
// round-12's in-loop split: same bf16h on same fp32 inputs)
template <int W>
__global__ __launch_bounds__(256) void split_swT(
    const float* __restrict__ sw, ushort* __restrict__ hi, ushort* __restrict__ lo)
{
    const int i = blockIdx.x * 256 + threadIdx.x;   // over 512*W
    float v[8];
#pragma unroll
    for (int r = 0; r < 8; ++r) v[r] = sw[(size_t)i * 8 + r];
#pragma unroll
    for (int r = 0; r < 8; ++r) {
        ushort h = bf16h(v[r]);
        hi[(size_t)r * 512 * W + i] = h;
        lo[(size_t)r * 512 * W + i] = bf16h(v[r] - bf16f(h));
    }
}

// phase A: MFMA, split-bf16 (3 products). 1536 wave-tasks:
// [layer][khalf][tile], tile fastest -> each block's 4 waves are 4 CONSECUTIVE
// tiles of the same layer+khalf+group -> identical B-fragment addresses ->
// L1/L2 hits for 3 of 4 waves. Spline weights pre-split (pure load path);
// gate/base weights split on the fly.
__global__ __launch_bounds__(256) void phaseA_kernel(
    const ushort* __restrict__ fe, const ushort* __restrict__ wsp,
    float* __restrict__ p0, float* __restrict__ p1,
    const float* __restrict__ w_ih0, const float* __restrict__ w_hh0,
    const float* __restrict__ kb0,
    const float* __restrict__ w_ih1, const float* __restrict__ w_hh1,
    const float* __restrict__ kb1, int s)
{
    const int lane = threadIdx.x & 63;
    const int wv   = __builtin_amdgcn_readfirstlane((int)(threadIdx.x >> 6));
    const int wid  = blockIdx.x * 4 + wv;            // 0..1535
    const bool isL1 = wid >= 768;
    if (isL1 ? (s < 1) : (s >= TT)) return;          // block-uniform
    const int rem   = isL1 ? wid - 768 : wid;
    const int khalf = rem >= 384 ? 1 : 0;
    const int tile  = rem - khalf * 384;             // 0..383
    const int IN = isL1 ? 512 : 128, W = IN + 512, KC = W >> 1, NSL = KC >> 5;

    float* p = (isL1 ? p1 : p0) + (size_t)khalf * 393216;
    const int m = lane & 15, kg = lane >> 4;
    const int o0 = tile * 16;

    // task decode
    const bool presplit = tile >= 128;
    const float* wrow_a = nullptr; const float* wrow_b = nullptr;
    const ushort *wa_h = nullptr, *wa_l = nullptr, *fhi, *flo;
    if (tile < 96) {                                  // gate rows (z features)
        wrow_a = (isL1 ? w_ih1 : w_ih0) + (size_t)(o0 + m) * IN;
        wrow_b = (isL1 ? w_hh1 : w_hh0) + (size_t)(o0 + m) * 512;
        fhi = fe + (isL1 ? FZ1H : FZ0H);  flo = fe + (isL1 ? FZ1L : FZ0L);
    } else if (tile < 128) {                          // base rows (silu features)
        wrow_a = (isL1 ? kb1 : kb0) + (size_t)((tile - 96) * 16 + m) * W;
        fhi = fe + (isL1 ? FS1H : FS0H);  flo = fe + (isL1 ? FS1L : FS0L);
    } else {                                          // spline rows (pre-split)
        const int rr = (tile - 128) >> 5, op = ((tile - 128) & 31) * 16 + m;
        const size_t ro = ((size_t)rr * 512 + op) * W;
        wa_h = wsp + (isL1 ? SWT1H : SWT0H) + ro;
        wa_l = wsp + (isL1 ? SWT1L : SWT0L) + ro;
        fhi = fe + (isL1 ? FB1H : FB0H) + (size_t)rr * 64 * W;
        flo = fe + (isL1 ? FB1L : FB0L) + (size_t)rr * 64 * W;
    }

    f32x4 acc[4] = {{0,0,0,0},{0,0,0,0},{0,0,0,0},{0,0,0,0}};
    const int kbase = khalf * KC;

    for (int sl = 0; sl < NSL; ++sl) {
        const int k0 = kbase + sl * 32;
        const int kk = k0 + kg * 8;
        short8v whi, wlo;
        if (presplit) {
            whi = *(const short8v*)(wa_h + kk);
            wlo = *(const short8v*)(wa_l + kk);
        } else {
            const float* wp = (tile < 96 && k0 >= IN) ? (wrow_b + (kk - IN))
                                                      : (wrow_a + kk);
            float4 wa = *(const float4*)wp;
            float4 wb4 = *(const float4*)(wp + 4);
            const float wvv[8] = {wa.x, wa.y, wa.z, wa.w, wb4.x, wb4.y, wb4.z, wb4.w};
#pragma unroll
            for (int j = 0; j < 8; ++j) {
                ushort h = bf16h(wvv[j]);
                whi[j] = (short)h;
                wlo[j] = (short)bf16h(wvv[j] - bf16f(h));
            }
        }
#pragma unroll
        for (int bt = 0; bt < 4; ++bt) {
            const size_t fidx = (size_t)(bt * 16 + m) * W + kk;
            short8v bh = *(const short8v*)(fhi + fidx);
            short8v bl = *(const short8v*)(flo + fidx);
            acc[bt] = __builtin_amdgcn_mfma_f32_16x16x32_bf16(whi, bh, acc[bt], 0, 0, 0);
            acc[bt] = __builtin_amdgcn_mfma_f32_16x16x32_bf16(whi, bl, acc[bt], 0, 0, 0);
            acc[bt] = __builtin_amdgcn_mfma_f32_16x16x32_bf16(wlo, bh, acc[bt], 0, 0, 0);
        }
    }

#pragma unroll
    for (int bt = 0; bt < 4; ++bt) {
        float* dst = p + (size_t)(bt * 16 + m) * 6144 + o0 + kg * 4;
        *(float4*)dst = (float4){acc[bt][0], acc[bt][1], acc[bt][2], acc[bt][3]};
    }
}

// phase B: cell updates (compile-time 2-slice unrolled) + feature gen; o-fast.
__global__ __launch_bounds__(256) void phaseB_kernel(
    ushort* __restrict__ fe, const float* __restrict__ p0, const float* __restrict__ p1,
    float* __restrict__ c0T, float* __restrict__ h1T, float* __restrict__ c1T,
    const float* __restrict__ b_ih0, const float* __restrict__ b_hh0,
    const float* __restrict__ b_ih1, const float* __restrict__ b_hh1,
    const float* __restrict__ x, int s)
{
    const int u = blockIdx.x * 256 + threadIdx.x;    // 288*256 = 73728
    if (u < 32768) {
        if (s >= TT) return;
        const int o = u & 511, b = u >> 9;
        auto P = [&](int rw) {
            return p0[(size_t)b * 6144 + rw] + p0[393216 + (size_t)b * 6144 + rw];
        };
        float si = P(o)        + b_ih0[o]        + b_hh0[o];
        float sf = P(512 + o)  + b_ih0[512 + o]  + b_hh0[512 + o];
        float sO = P(1024 + o) + b_ih0[1024 + o] + b_hh0[1024 + o];
        float sk = P(1536 + o);
#pragma unroll
        for (int rr = 0; rr < 8; ++rr) sk += P(2048 + rr * 512 + o);
        float ig = sigmoidf_(si), fg = sigmoidf_(sf), og = sigmoidf_(sO);
        float c = fg * c0T[(size_t)b * 512 + o] + ig * sk;
        c0T[(size_t)b * 512 + o] = c;
        float z = og * tanhf(c);
        write_featsT(z, fe, FZ1H, FZ1L, FS1H, FS1L, FB1H, FB1L,
                     65536, (size_t)b * 1024 + o);            // L1 input, t=s
        write_featsT(z, fe, FZ0H, FZ0L, FS0H, FS0L, FB0H, FB0L,
                     40960, (size_t)b * 640 + 128 + o);       // L0 hidden, t=s+1
    } else if (u < 65536) {
        if (s < 1) return;
        const int v = u - 32768, o = v & 511, b = v >> 9;
        auto P = [&](int rw) {
            return p1[(size_t)b * 6144 + rw] + p1[393216 + (size_t)b * 6144 + rw];
        };
        float si = P(o)        + b_ih1[o]        + b_hh1[o];
        float sf = P(512 + o)  + b_ih1[512 + o]  + b_hh1[512 + o];
        float sO = P(1024 + o) + b_ih1[1024 + o] + b_hh1[1024 + o];
        float sk = P(1536 + o);
#pragma unroll
        for (int rr = 0; rr < 8; ++rr) sk += P(2048 + rr * 512 + o);
        float ig = sigmoidf_(si), fg = sigmoidf_(sf), og = sigmoidf_(sO);
        float c = fg * c1T[(size_t)b * 512 + o] + ig * sk;
        c1T[(size_t)b * 512 + o] = c;
        float z = og * tanhf(c);
        h1T[(size_t)b * 512 + o] = z;
        write_featsT(z, fe, FZ1H, FZ1L, FS1H, FS1L, FB1H, FB1L,
                     65536, (size_t)b * 1024 + 512 + o);      // L1 hidden, t=s
    } else {
        if (s + 1 >= TT) return;
        const int v = u - 65536, k = v & 127, b = v >> 7;
        float z = x[((size_t)b * TT + (s + 1)) * 128 + k];
        write_featsT(z, fe, FZ0H, FZ0L, FS0H, FS0L, FB0H, FB0L,
                     40960, (size_t)b * 640 + k);             // L0 x, t=s+1
    }
}

// out[b][jo] = h1T[b] . fc_w[jo] + fc_b[jo]  (fp32 out)
__global__ __launch_bounds__(256) void final_fc(
    const float* __restrict__ h1T, const float* __restrict__ fc_w,
    const float* __restrict__ fc_b, float* __restrict__ out)
{
    const int gid = blockIdx.x * 256 + threadIdx.x;   // 8192
    const int b = gid & 63, jo = gid >> 6;
    float a = fc_b[jo];
    const float* hr = h1T + (size_t)b * 512;
    const float* wr = fc_w + (size_t)jo * 512;
    for (int o = 0; o < 512; o += 4) {
        float4 h4 = *(const float4*)(hr + o);
        float4 w4 = *(const float4*)(wr + o);
        a = fmaf(h4.x, w4.x, a); a = fmaf(h4.y, w4.y, a);
        a = fmaf(h4.z, w4.z, a); a = fmaf(h4.w, w4.w, a);
    }
    out[(size_t)b * 128 + jo] = a;
}

} // namespace

extern "C" void kernel_launch(void* const* d_in, const int* in_sizes, int n_in,
                              void* d_out, int out_size, void* d_ws, size_t ws_size,
                              hipStream_t stream) {
    (void)out_size;
    float* out = (float*)d_out;

    static const int EXP_SIZES[15] = {
        64 * 256 * 128, 1536 * 128, 1536 * 512, 1536, 1536,
        512 * 640, 512 * 640 * 8,
        1536 * 512, 1536 * 512, 1536, 1536,
        512 * 1024, 512 * 1024 * 8,
        128 * 512, 128
    };
    if (n_in != 15) { sentinel_kernel<<<32, 256, 0, stream>>>(out, 111.0f); return; }
    for (int i = 0; i < 15; ++i)
        if (in_sizes[i] != EXP_SIZES[i]) {
            sentinel_kernel<<<32, 256, 0, stream>>>(out, 200.0f * (i + 1)); return;
        }
    if (ws_size < WS_NEED) { sentinel_kernel<<<32, 256, 0, stream>>>(out, 7777.0f); return; }

    const float* x     = (const float*)d_in[0];
    const float* w_ih0 = (const float*)d_in[1];
    const float* w_hh0 = (const float*)d_in[2];
    const float* b_ih0 = (const float*)d_in[3];
    const float* b_hh0 = (const float*)d_in[4];
    const float* kb0   = (const float*)d_in[5];
    const float* ksp0  = (const float*)d_in[6];
    const float* w_ih1 = (const float*)d_in[7];
    const float* w_hh1 = (const float*)d_in[8];
    const float* b_ih1 = (const float*)d_in[9];
    const float* b_hh1 = (const float*)d_in[10];
    const float* kb1   = (const float*)d_in[11];
    const float* ksp1  = (const float*)d_in[12];
    const float* fc_w  = (const float*)d_in[13];
    const float* fc_b  = (const float*)d_in[14];

    float* ws = (float*)d_ws;
    float* st = ws + S_ST;
    float* p0 = ws + S_P0;
    float* p1 = ws + S_P1;
    ushort* wsp = (ushort*)(ws + S_WSP);
    ushort* fe  = (ushort*)(ws + S_FEAT);

    prologue_kernel<<<672, 256, 0, stream>>>(x, st, fe);
    split_swT<640><<<1280, 256, 0, stream>>>(ksp0, wsp + SWT0H, wsp + SWT0L);
    split_swT<1024><<<2048, 256, 0, stream>>>(ksp1, wsp + SWT1H, wsp + SWT1L);

    for (int s = 0; s <= TT; ++s) {
        phaseA_kernel<<<384, 256, 0, stream>>>(fe, wsp, p0, p1,
            w_ih0, w_hh0, kb0, w_ih1, w_hh1, kb1, s);
        phaseB_kernel<<<288, 256, 0, stream>>>(fe, p0, p1, st, st + 32768,
            st + 65536, b_ih0, b_hh0, b_ih1, b_hh1, x, s);
    }

    final_fc<<<32, 256, 0, stream>>>(st + 32768, fc_w, fc_b, out);
}

// Round 15
// 9860.851 us; speedup vs baseline: 1.1886x; 1.1886x over previous
//
#include <hip/hip_runtime.h>
#include <math.h>
#include <stdint.h>

namespace {

typedef __attribute__((ext_vector_type(8))) short short8v;   // 8 bf16 = 4 VGPR
typedef __attribute__((ext_vector_type(4))) float f32x4;

constexpr int TT = 256;

// ---- ws float offsets (total 9,551,872 floats = 38.2 MB, proven) ----
constexpr size_t S_ST   = 0;          // c0T,h1T,c1T [3][64][512]
constexpr size_t S_P0   = 98304;      // [2][64][6144]
constexpr size_t S_P1   = 884736;     // [2][64][6144]
constexpr size_t S_WSP  = 1671168;    // 13,631,488 ushorts: spline weights hi/lo
constexpr size_t S_FEAT = 8486912;    // 2,129,920 ushorts: features
constexpr size_t WS_NEED = 9551872ull * 4;

// ushort offsets inside wsp (spline split weights, [8][512][W])
constexpr size_t SWT0H = 0,       SWT0L = 2621440;
constexpr size_t SWT1H = 5242880, SWT1L = 9437184;

// ---- ushort offsets within FEAT ----
constexpr size_t FZ0H = 0,       FZ0L = 40960,  FS0H = 81920,  FS0L = 122880;
constexpr size_t FB0H = 163840,  FB0L = 491520;                 // planes 64*640
constexpr size_t L1F  = 819200;
constexpr size_t FZ1H = L1F,          FZ1L = L1F + 65536;
constexpr size_t FS1H = L1F + 131072, FS1L = L1F + 196608;
constexpr size_t FB1H = L1F + 262144, FB1L = L1F + 786432;      // planes 64*1024

__device__ __forceinline__ float sigmoidf_(float v) { return 1.0f / (1.0f + expf(-v)); }

__device__ __forceinline__ ushort bf16h(float v) {          // RNE f32 -> bf16 bits
    uint32_t u = __float_as_uint(v);
    return (ushort)((u + 0x7fffu + ((u >> 16) & 1u)) >> 16);
}
__device__ __forceinline__ float bf16f(ushort h) { return __uint_as_float(((uint32_t)h) << 16); }
__device__ __forceinline__ void put2(ushort* hi, ushort* lo, size_t idx, float v) {
    ushort h = bf16h(v); hi[idx] = h; lo[idx] = bf16h(v - bf16f(h));
}

// Cox-de Boor, GRID_SIZE=5, ORDER=3 (verified rounds 7-14)
__device__ __forceinline__ void bspline8(float x, float* out) {
    const float KG[12] = {-2.2f,-1.8f,-1.4f,-1.0f,-0.6f,-0.2f,
                           0.2f, 0.6f, 1.0f, 1.4f, 1.8f, 2.2f};
    float b[11];
#pragma unroll
    for (int i = 0; i < 11; ++i)
        b[i] = (x >= KG[i] && x < KG[i + 1]) ? 1.0f : 0.0f;
#pragma unroll
    for (int p = 1; p <= 3; ++p) {
#pragma unroll
        for (int i = 0; i + p < 11; ++i) {
            float l = (x - KG[i])         * (1.0f / (KG[i + p] - KG[i]));
            float r = (KG[i + p + 1] - x) * (1.0f / (KG[i + p + 1] - KG[i + 1]));
            b[i] = l * b[i] + r * b[i + 1];
        }
    }
#pragma unroll
    for (int i = 0; i < 8; ++i) out[i] = b[i];
}

__device__ __forceinline__ void write_featsT(float z, ushort* fe,
        size_t zh, size_t zl, size_t sh, size_t sl, size_t bh, size_t bl,
        size_t pstride, size_t idx)
{
    put2(fe + zh, fe + zl, idx, z);
    put2(fe + sh, fe + sl, idx, z / (1.0f + expf(-z)));
    float bs[8];
    bspline8(z, bs);
#pragma unroll
    for (int r = 0; r < 8; ++r)
        put2(fe + bh + (size_t)r * pstride, fe + bl + (size_t)r * pstride, idx, bs[r]);
}

__global__ __launch_bounds__(256) void sentinel_kernel(float* out, float v) {
    int i = blockIdx.x * 256 + threadIdx.x;
    if (i < 8192) out[i] = v;
}

// states zero + t=0 x-features + zero-state hidden features for both layers
__global__ __launch_bounds__(256) void prologue_kernel(
    const float* __restrict__ x, float* __restrict__ st, ushort* __restrict__ fe)
{
    const int g = blockIdx.x * 256 + threadIdx.x;    // 672*256 = 172032
    if (g < 98304) {
        st[g] = 0.0f;                                // c0T,h1T,c1T
    } else if (g < 106496) {                         // t=0 x feats (k<128)
        const int i = g - 98304, k = i & 127, b = i >> 7;
        write_featsT(x[((size_t)b * TT) * 128 + k], fe,
                     FZ0H, FZ0L, FS0H, FS0L, FB0H, FB0L, 40960, (size_t)b * 640 + k);
    } else if (g < 139264) {                         // L0 hidden feats h0(-1)=0
        const int i = g - 106496, o = i & 511, b = i >> 9;
        write_featsT(0.0f, fe, FZ0H, FZ0L, FS0H, FS0L, FB0H, FB0L,
                     40960, (size_t)b * 640 + 128 + o);
    } else {                                         // L1 hidden feats h1(-1)=0
        const int i = g - 139264, o = i & 511, b = i >> 9;
        write_featsT(0.0f, fe, FZ1H, FZ1L, FS1H, FS1L, FB1H, FB1L,
                     65536, (size_t)b * 1024 + 512 + o);
    }
}

// ksp [512][W][8] fp32 -> hi/lo bf16 [8][512][W]
template <int W>
__global__ __launch_bounds__(256) void split_swT(
    const float* __restrict__ sw, ushort* __restrict__ hi, ushort* __restrict__ lo)
{
    const int i = blockIdx.x * 256 + threadIdx.x;   // over 512*W
    float v[8];
#pragma unroll
    for (int r = 0; r < 8; ++r) v[r] = sw[(size_t)i * 8 + r];
#pragma unroll
    for (int r = 0; r < 8; ++r) {
        ushort h = bf16h(v[r]);
        hi[(size_t)r * 512 * W + i] = h;
        lo[(size_t)r * 512 * W + i] = bf16h(v[r] - bf16f(h));
    }
}

// phase A: MFMA, split-bf16 (3 products). Block = 1 tile (block-uniform),
// 4 waves = {khalf x bt-half}; grid 768 = 3.0 blocks/CU balanced; 3072 waves.
// bt-split adds no memory traffic (partials disjoint, weights L1-shared) and
// is bit-identical arithmetic. Spline weights pre-split; gate/base on-the-fly.
__global__ __launch_bounds__(256) void phaseA_kernel(
    const ushort* __restrict__ fe, const ushort* __restrict__ wsp,
    float* __restrict__ p0, float* __restrict__ p1,
    const float* __restrict__ w_ih0, const float* __restrict__ w_hh0,
    const float* __restrict__ kb0,
    const float* __restrict__ w_ih1, const float* __restrict__ w_hh1,
    const float* __restrict__ kb1, int s)
{
    const int lane = threadIdx.x & 63;
    const int wv   = __builtin_amdgcn_readfirstlane((int)(threadIdx.x >> 6));
    const int bid  = blockIdx.x;                     // 0..767
    const bool isL1 = bid >= 384;
    if (isL1 ? (s < 1) : (s >= TT)) return;          // block-uniform
    const int tile  = isL1 ? bid - 384 : bid;        // 0..383
    const int khalf = (wv >> 1) & 1;
    const int bth   = wv & 1;                        // bt in {2*bth, 2*bth+1}
    const int IN = isL1 ? 512 : 128, W = IN + 512, KC = W >> 1, NSL = KC >> 5;

    float* p = (isL1 ? p1 : p0) + (size_t)khalf * 393216;
    const int m = lane & 15, kg = lane >> 4;
    const int o0 = tile * 16;

    const bool presplit = tile >= 128;
    const float* wrow_a = nullptr; const float* wrow_b = nullptr;
    const ushort *wa_h = nullptr, *wa_l = nullptr, *fhi, *flo;
    if (tile < 96) {                                  // gate rows (z features)
        wrow_a = (isL1 ? w_ih1 : w_ih0) + (size_t)(o0 + m) * IN;
        wrow_b = (isL1 ? w_hh1 : w_hh0) + (size_t)(o0 + m) * 512;
        fhi = fe + (isL1 ? FZ1H : FZ0H);  flo = fe + (isL1 ? FZ1L : FZ0L);
    } else if (tile < 128) {                          // base rows (silu features)
        wrow_a = (isL1 ? kb1 : kb0) + (size_t)((tile - 96) * 16 + m) * W;
        fhi = fe + (isL1 ? FS1H : FS0H);  flo = fe + (isL1 ? FS1L : FS0L);
    } else {                                          // spline rows (pre-split)
        const int rr = (tile - 128) >> 5, op = ((tile - 128) & 31) * 16 + m;
        const size_t ro = ((size_t)rr * 512 + op) * W;
        wa_h = wsp + (isL1 ? SWT1H : SWT0H) + ro;
        wa_l = wsp + (isL1 ? SWT1L : SWT0L) + ro;
        fhi = fe + (isL1 ? FB1H : FB0H) + (size_t)rr * 64 * W;
        flo = fe + (isL1 ? FB1L : FB0L) + (size_t)rr * 64 * W;
    }

    f32x4 acc[2] = {{0,0,0,0},{0,0,0,0}};
    const int kbase = khalf * KC;

    for (int sl = 0; sl < NSL; ++sl) {
        const int k0 = kbase + sl * 32;
        const int kk = k0 + kg * 8;
        short8v whi, wlo;
        if (presplit) {
            whi = *(const short8v*)(wa_h + kk);
            wlo = *(const short8v*)(wa_l + kk);
        } else {
            const float* wp = (tile < 96 && k0 >= IN) ? (wrow_b + (kk - IN))
                                                      : (wrow_a + kk);
            float4 wa = *(const float4*)wp;
            float4 wb4 = *(const float4*)(wp + 4);
            const float wvv[8] = {wa.x, wa.y, wa.z, wa.w, wb4.x, wb4.y, wb4.z, wb4.w};
#pragma unroll
            for (int j = 0; j < 8; ++j) {
                ushort h = bf16h(wvv[j]);
                whi[j] = (short)h;
                wlo[j] = (short)bf16h(wvv[j] - bf16f(h));
            }
        }
#pragma unroll
        for (int bt2 = 0; bt2 < 2; ++bt2) {
            const int bt = bth * 2 + bt2;
            const size_t fidx = (size_t)(bt * 16 + m) * W + kk;
            short8v bh = *(const short8v*)(fhi + fidx);
            short8v bl = *(const short8v*)(flo + fidx);
            acc[bt2] = __builtin_amdgcn_mfma_f32_16x16x32_bf16(whi, bh, acc[bt2], 0, 0, 0);
            acc[bt2] = __builtin_amdgcn_mfma_f32_16x16x32_bf16(whi, bl, acc[bt2], 0, 0, 0);
            acc[bt2] = __builtin_amdgcn_mfma_f32_16x16x32_bf16(wlo, bh, acc[bt2], 0, 0, 0);
        }
    }

#pragma unroll
    for (int bt2 = 0; bt2 < 2; ++bt2) {
        const int bt = bth * 2 + bt2;
        float* dst = p + (size_t)(bt * 16 + m) * 6144 + o0 + kg * 4;
        *(float4*)dst = (float4){acc[bt2][0], acc[bt2][1], acc[bt2][2], acc[bt2][3]};
    }
}

// phase B: cell updates (compile-time 2-slice unrolled) + feature gen; o-fast.
__global__ __launch_bounds__(256) void phaseB_kernel(
    ushort* __restrict__ fe, const float* __restrict__ p0, const float* __restrict__ p1,
    float* __restrict__ c0T, float* __restrict__ h1T, float* __restrict__ c1T,
    const float* __restrict__ b_ih0, const float* __restrict__ b_hh0,
    const float* __restrict__ b_ih1, const float* __restrict__ b_hh1,
    const float* __restrict__ x, int s)
{
    const int u = blockIdx.x * 256 + threadIdx.x;    // 288*256 = 73728
    if (u < 32768) {
        if (s >= TT) return;
        const int o = u & 511, b = u >> 9;
        auto P = [&](int rw) {
            return p0[(size_t)b * 6144 + rw] + p0[393216 + (size_t)b * 6144 + rw];
        };
        float si = P(o)        + b_ih0[o]        + b_hh0[o];
        float sf = P(512 + o)  + b_ih0[512 + o]  + b_hh0[512 + o];
        float sO = P(1024 + o) + b_ih0[1024 + o] + b_hh0[1024 + o];
        float sk = P(1536 + o);
#pragma unroll
        for (int rr = 0; rr < 8; ++rr) sk += P(2048 + rr * 512 + o);
        float ig = sigmoidf_(si), fg = sigmoidf_(sf), og = sigmoidf_(sO);
        float c = fg * c0T[(size_t)b * 512 + o] + ig * sk;
        c0T[(size_t)b * 512 + o] = c;
        float z = og * tanhf(c);
        write_featsT(z, fe, FZ1H, FZ1L, FS1H, FS1L, FB1H, FB1L,
                     65536, (size_t)b * 1024 + o);            // L1 input, t=s
        write_featsT(z, fe, FZ0H, FZ0L, FS0H, FS0L, FB0H, FB0L,
                     40960, (size_t)b * 640 + 128 + o);       // L0 hidden, t=s+1
    } else if (u < 65536) {
        if (s < 1) return;
        const int v = u - 32768, o = v & 511, b = v >> 9;
        auto P = [&](int rw) {
            return p1[(size_t)b * 6144 + rw] + p1[393216 + (size_t)b * 6144 + rw];
        };
        float si = P(o)        + b_ih1[o]        + b_hh1[o];
        float sf = P(512 + o)  + b_ih1[512 + o]  + b_hh1[512 + o];
        float sO = P(1024 + o) + b_ih1[1024 + o] + b_hh1[1024 + o];
        float sk = P(1536 + o);
#pragma unroll
        for (int rr = 0; rr < 8; ++rr) sk += P(2048 + rr * 512 + o);
        float ig = sigmoidf_(si), fg = sigmoidf_(sf), og = sigmoidf_(sO);
        float c = fg * c1T[(size_t)b * 512 + o] + ig * sk;
        c1T[(size_t)b * 512 + o] = c;
        float z = og * tanhf(c);
        h1T[(size_t)b * 512 + o] = z;
        write_featsT(z, fe, FZ1H, FZ1L, FS1H, FS1L, FB1H, FB1L,
                     65536, (size_t)b * 1024 + 512 + o);      // L1 hidden, t=s
    } else {
        if (s + 1 >= TT) return;
        const int v = u - 65536, k = v & 127, b = v >> 7;
        float z = x[((size_t)b * TT + (s + 1)) * 128 + k];
        write_featsT(z, fe, FZ0H, FZ0L, FS0H, FS0L, FB0H, FB0L,
                     40960, (size_t)b * 640 + k);             // L0 x, t=s+1
    }
}

// out[b][jo] = h1T[b] . fc_w[jo] + fc_b[jo]  (fp32 out)
__global__ __launch_bounds__(256) void final_fc(
    const float* __restrict__ h1T, const float* __restrict__ fc_w,
    const float* __restrict__ fc_b, float* __restrict__ out)
{
    const int gid = blockIdx.x * 256 + threadIdx.x;   // 8192
    const int b = gid & 63, jo = gid >> 6;
    float a = fc_b[jo];
    const float* hr = h1T + (size_t)b * 512;
    const float* wr = fc_w + (size_t)jo * 512;
    for (int o = 0; o < 512; o += 4) {
        float4 h4 = *(const float4*)(hr + o);
        float4 w4 = *(const float4*)(wr + o);
        a = fmaf(h4.x, w4.x, a); a = fmaf(h4.y, w4.y, a);
        a = fmaf(h4.z, w4.z, a); a = fmaf(h4.w, w4.w, a);
    }
    out[(size_t)b * 128 + jo] = a;
}

} // namespace

extern "C" void kernel_launch(void* const* d_in, const int* in_sizes, int n_in,
                              void* d_out, int out_size, void* d_ws, size_t ws_size,
                              hipStream_t stream) {
    (void)out_size;
    float* out = (float*)d_out;

    static const int EXP_SIZES[15] = {
        64 * 256 * 128, 1536 * 128, 1536 * 512, 1536, 1536,
        512 * 640, 512 * 640 * 8,
        1536 * 512, 1536 * 512, 1536, 1536,
        512 * 1024, 512 * 1024 * 8,
        128 * 512, 128
    };
    if (n_in != 15) { sentinel_kernel<<<32, 256, 0, stream>>>(out, 111.0f); return; }
    for (int i = 0; i < 15; ++i)
        if (in_sizes[i] != EXP_SIZES[i]) {
            sentinel_kernel<<<32, 256, 0, stream>>>(out, 200.0f * (i + 1)); return;
        }
    if (ws_size < WS_NEED) { sentinel_kernel<<<32, 256, 0, stream>>>(out, 7777.0f); return; }

    const float* x     = (const float*)d_in[0];
    const float* w_ih0 = (const float*)d_in[1];
    const float* w_hh0 = (const float*)d_in[2];
    const float* b_ih0 = (const float*)d_in[3];
    const float* b_hh0 = (const float*)d_in[4];
    const float* kb0   = (const float*)d_in[5];
    const float* ksp0  = (const float*)d_in[6];
    const float* w_ih1 = (const float*)d_in[7];
    const float* w_hh1 = (const float*)d_in[8];
    const float* b_ih1 = (const float*)d_in[9];
    const float* b_hh1 = (const float*)d_in[10];
    const float* kb1   = (const float*)d_in[11];
    const float* ksp1  = (const float*)d_in[12];
    const float* fc_w  = (const float*)d_in[13];
    const float* fc_b  = (const float*)d_in[14];

    float* ws = (float*)d_ws;
    float* st = ws + S_ST;
    float* p0 = ws + S_P0;
    float* p1 = ws + S_P1;
    ushort* wsp = (ushort*)(ws + S_WSP);
    ushort* fe  = (ushort*)(ws + S_FEAT);

    prologue_kernel<<<672, 256, 0, stream>>>(x, st, fe);
    split_swT<640><<<1280, 256, 0, stream>>>(ksp0, wsp + SWT0H, wsp + SWT0L);
    split_swT<1024><<<2048, 256, 0, stream>>>(ksp1, wsp + SWT1H, wsp + SWT1L);

    for (int s = 0; s <= TT; ++s) {
        phaseA_kernel<<<768, 256, 0, stream>>>(fe, wsp, p0, p1,
            w_ih0, w_hh0, kb0, w_ih1, w_hh1, kb1, s);
        phaseB_kernel<<<288, 256, 0, stream>>>(fe, p0, p1, st, st + 32768,
            st + 65536, b_ih0, b_hh0, b_ih1, b_hh1, x, s);
    }

    final_fc<<<32, 256, 0, stream>>>(st + 32768, fc_w, fc_b, out);
}

// Round 16
// 9317.162 us; speedup vs baseline: 1.2580x; 1.0584x over previous
//
#include <hip/hip_runtime.h>
#include <math.h>
#include <stdint.h>

namespace {

typedef __attribute__((ext_vector_type(8))) short short8v;   // 8 bf16 = 4 VGPR
typedef __attribute__((ext_vector_type(4))) float f32x4;

constexpr int TT = 256;

// ---- ws float offsets (total 9,551,872 floats = 38.2 MB, proven) ----
constexpr size_t S_ST   = 0;          // c0T,h1T,c1T [3][64][512]
constexpr size_t S_P0   = 98304;      // [2][64][6144]
constexpr size_t S_P1   = 884736;     // [2][64][6144]
constexpr size_t S_WSP  = 1671168;    // 13,631,488 ushorts: spline weights hi/lo
constexpr size_t S_FEAT = 8486912;    // 2,129,920 ushorts: features
constexpr size_t WS_NEED = 9551872ull * 4;

// ushort offsets inside wsp (spline split weights, [8][512][W])
constexpr size_t SWT0H = 0,       SWT0L = 2621440;
constexpr size_t SWT1H = 5242880, SWT1L = 9437184;

// ---- ushort offsets within FEAT ----
constexpr size_t FZ0H = 0,       FZ0L = 40960,  FS0H = 81920,  FS0L = 122880;
constexpr size_t FB0H = 163840,  FB0L = 491520;                 // planes 64*640
constexpr size_t L1F  = 819200;
constexpr size_t FZ1H = L1F,          FZ1L = L1F + 65536;
constexpr size_t FS1H = L1F + 131072, FS1L = L1F + 196608;
constexpr size_t FB1H = L1F + 262144, FB1L = L1F + 786432;      // planes 64*1024

__device__ __forceinline__ float sigmoidf_(float v) { return 1.0f / (1.0f + expf(-v)); }

__device__ __forceinline__ ushort bf16h(float v) {          // RNE f32 -> bf16 bits
    uint32_t u = __float_as_uint(v);
    return (ushort)((u + 0x7fffu + ((u >> 16) & 1u)) >> 16);
}
__device__ __forceinline__ float bf16f(ushort h) { return __uint_as_float(((uint32_t)h) << 16); }
__device__ __forceinline__ void put2(ushort* hi, ushort* lo, size_t idx, float v) {
    ushort h = bf16h(v); hi[idx] = h; lo[idx] = bf16h(v - bf16f(h));
}

// Cox-de Boor, GRID_SIZE=5, ORDER=3 (verified rounds 7-15)
__device__ __forceinline__ void bspline8(float x, float* out) {
    const float KG[12] = {-2.2f,-1.8f,-1.4f,-1.0f,-0.6f,-0.2f,
                           0.2f, 0.6f, 1.0f, 1.4f, 1.8f, 2.2f};
    float b[11];
#pragma unroll
    for (int i = 0; i < 11; ++i)
        b[i] = (x >= KG[i] && x < KG[i + 1]) ? 1.0f : 0.0f;
#pragma unroll
    for (int p = 1; p <= 3; ++p) {
#pragma unroll
        for (int i = 0; i + p < 11; ++i) {
            float l = (x - KG[i])         * (1.0f / (KG[i + p] - KG[i]));
            float r = (KG[i + p + 1] - x) * (1.0f / (KG[i + p + 1] - KG[i + 1]));
            b[i] = l * b[i] + r * b[i + 1];
        }
    }
#pragma unroll
    for (int i = 0; i < 8; ++i) out[i] = b[i];
}

__device__ __forceinline__ void write_featsT(float z, ushort* fe,
        size_t zh, size_t zl, size_t sh, size_t sl, size_t bh, size_t bl,
        size_t pstride, size_t idx)
{
    put2(fe + zh, fe + zl, idx, z);
    put2(fe + sh, fe + sl, idx, z / (1.0f + expf(-z)));
    float bs[8];
    bspline8(z, bs);
#pragma unroll
    for (int r = 0; r < 8; ++r)
        put2(fe + bh + (size_t)r * pstride, fe + bl + (size_t)r * pstride, idx, bs[r]);
}

__global__ __launch_bounds__(256) void sentinel_kernel(float* out, float v) {
    int i = blockIdx.x * 256 + threadIdx.x;
    if (i < 8192) out[i] = v;
}

// states zero + t=0 x-features + zero-state hidden features for both layers
__global__ __launch_bounds__(256) void prologue_kernel(
    const float* __restrict__ x, float* __restrict__ st, ushort* __restrict__ fe)
{
    const int g = blockIdx.x * 256 + threadIdx.x;    // 672*256 = 172032
    if (g < 98304) {
        st[g] = 0.0f;                                // c0T,h1T,c1T
    } else if (g < 106496) {                         // t=0 x feats (k<128)
        const int i = g - 98304, k = i & 127, b = i >> 7;
        write_featsT(x[((size_t)b * TT) * 128 + k], fe,
                     FZ0H, FZ0L, FS0H, FS0L, FB0H, FB0L, 40960, (size_t)b * 640 + k);
    } else if (g < 139264) {                         // L0 hidden feats h0(-1)=0
        const int i = g - 106496, o = i & 511, b = i >> 9;
        write_featsT(0.0f, fe, FZ0H, FZ0L, FS0H, FS0L, FB0H, FB0L,
                     40960, (size_t)b * 640 + 128 + o);
    } else {                                         // L1 hidden feats h1(-1)=0
        const int i = g - 139264, o = i & 511, b = i >> 9;
        write_featsT(0.0f, fe, FZ1H, FZ1L, FS1H, FS1L, FB1H, FB1L,
                     65536, (size_t)b * 1024 + 512 + o);
    }
}

// ksp [512][W][8] fp32 -> hi/lo bf16 [8][512][W]
template <int W>
__global__ __launch_bounds__(256) void split_swT(
    const float* __restrict__ sw, ushort* __restrict__ hi, ushort* __restrict__ lo)
{
    const int i = blockIdx.x * 256 + threadIdx.x;   // over 512*W
    float v[8];
#pragma unroll
    for (int r = 0; r < 8; ++r) v[r] = sw[(size_t)i * 8 + r];
#pragma unroll
    for (int r = 0; r < 8; ++r) {
        ushort h = bf16h(v[r]);
        hi[(size_t)r * 512 * W + i] = h;
        lo[(size_t)r * 512 * W + i] = bf16h(v[r] - bf16f(h));
    }
}

// Fully-unrolled K-loop: IN/KHALF/MODE compile-time -> NSL, k0, ih/hh boundary
// all constexpr; compiler can pipeline loads across slices with counted waits.
// MODE: 0 = gates (fp32 w_ih|w_hh, on-the-fly split), 1 = base (fp32 kb),
//       2 = spline (pre-split hi/lo bf16).
template <int IN, int KHALF, int MODE>
__device__ __forceinline__ void kloopA(
    const float* __restrict__ wrow_a, const float* __restrict__ wrow_b,
    const ushort* __restrict__ wa_h, const ushort* __restrict__ wa_l,
    const ushort* __restrict__ fhi, const ushort* __restrict__ flo,
    int m, int kg, float* __restrict__ pdst)
{
    constexpr int W   = IN + 512;
    constexpr int KC  = W >> 1;
    constexpr int NSL = KC >> 5;
    constexpr int KB  = KHALF * KC;

    f32x4 acc[4] = {{0,0,0,0},{0,0,0,0},{0,0,0,0},{0,0,0,0}};

#pragma unroll
    for (int sl = 0; sl < NSL; ++sl) {
        const int k0 = KB + sl * 32;           // compile-time constant
        const int kk = k0 + kg * 8;
        short8v whi, wlo;
        if constexpr (MODE == 2) {
            whi = *(const short8v*)(wa_h + kk);
            wlo = *(const short8v*)(wa_l + kk);
        } else {
            const float* wp;
            if constexpr (MODE == 0) {
                wp = (k0 >= IN) ? (wrow_b + (kk - IN)) : (wrow_a + kk);  // folds
            } else {
                wp = wrow_a + kk;
            }
            float4 wa = *(const float4*)wp;
            float4 wb4 = *(const float4*)(wp + 4);
            const float wvv[8] = {wa.x, wa.y, wa.z, wa.w, wb4.x, wb4.y, wb4.z, wb4.w};
#pragma unroll
            for (int j = 0; j < 8; ++j) {
                ushort h = bf16h(wvv[j]);
                whi[j] = (short)h;
                wlo[j] = (short)bf16h(wvv[j] - bf16f(h));
            }
        }
#pragma unroll
        for (int bt = 0; bt < 4; ++bt) {
            const size_t fidx = (size_t)(bt * 16 + m) * W + kk;
            short8v bh = *(const short8v*)(fhi + fidx);
            short8v bl = *(const short8v*)(flo + fidx);
            acc[bt] = __builtin_amdgcn_mfma_f32_16x16x32_bf16(whi, bh, acc[bt], 0, 0, 0);
            acc[bt] = __builtin_amdgcn_mfma_f32_16x16x32_bf16(whi, bl, acc[bt], 0, 0, 0);
            acc[bt] = __builtin_amdgcn_mfma_f32_16x16x32_bf16(wlo, bh, acc[bt], 0, 0, 0);
        }
    }

#pragma unroll
    for (int bt = 0; bt < 4; ++bt) {
        float* dst = pdst + (size_t)(bt * 16 + m) * 6144 + kg * 4;
        *(float4*)dst = (float4){acc[bt][0], acc[bt][1], acc[bt][2], acc[bt][3]};
    }
}

template <int IN>
__device__ __forceinline__ void phaseA_impl(
    int tile, int khalf, int lane,
    const ushort* __restrict__ fe, const ushort* __restrict__ wsp,
    const float* __restrict__ w_ih, const float* __restrict__ w_hh,
    const float* __restrict__ kb, float* __restrict__ p,
    size_t FZH, size_t FZL, size_t FSH, size_t FSL, size_t FBH, size_t FBL,
    size_t SWH, size_t SWL)
{
    constexpr int W = IN + 512;
    const int m = lane & 15, kg = lane >> 4;
    const int o0 = tile * 16;
    float* pdst = p + (size_t)khalf * 393216 + o0;

    if (tile < 96) {                                  // gate rows (z features)
        const float* wa = w_ih + (size_t)(o0 + m) * IN;
        const float* wb = w_hh + (size_t)(o0 + m) * 512;
        const ushort* fhi = fe + FZH;
        const ushort* flo = fe + FZL;
        if (khalf) kloopA<IN,1,0>(wa, wb, nullptr, nullptr, fhi, flo, m, kg, pdst);
        else       kloopA<IN,0,0>(wa, wb, nullptr, nullptr, fhi, flo, m, kg, pdst);
    } else if (tile < 128) {                          // base rows (silu features)
        const float* wa = kb + (size_t)((tile - 96) * 16 + m) * W;
        const ushort* fhi = fe + FSH;
        const ushort* flo = fe + FSL;
        if (khalf) kloopA<IN,1,1>(wa, nullptr, nullptr, nullptr, fhi, flo, m, kg, pdst);
        else       kloopA<IN,0,1>(wa, nullptr, nullptr, nullptr, fhi, flo, m, kg, pdst);
    } else {                                          // spline rows (pre-split)
        const int rr = (tile - 128) >> 5, op = ((tile - 128) & 31) * 16 + m;
        const size_t ro = ((size_t)rr * 512 + op) * W;
        const ushort* wah = wsp + SWH + ro;
        const ushort* wal = wsp + SWL + ro;
        const ushort* fhi = fe + FBH + (size_t)rr * 64 * W;
        const ushort* flo = fe + FBL + (size_t)rr * 64 * W;
        if (khalf) kloopA<IN,1,2>(nullptr, nullptr, wah, wal, fhi, flo, m, kg, pdst);
        else       kloopA<IN,0,2>(nullptr, nullptr, wah, wal, fhi, flo, m, kg, pdst);
    }
}

// phase A: 768 blocks x 128 thr. Block = one 16-row tile (block-uniform layer);
// wave = khalf. acc[4] (all 4 batch-tiles) per wave = round-12 geometry.
__global__ __launch_bounds__(128) void phaseA_kernel(
    const ushort* __restrict__ fe, const ushort* __restrict__ wsp,
    float* __restrict__ p0, float* __restrict__ p1,
    const float* __restrict__ w_ih0, const float* __restrict__ w_hh0,
    const float* __restrict__ kb0,
    const float* __restrict__ w_ih1, const float* __restrict__ w_hh1,
    const float* __restrict__ kb1, int s)
{
    const int lane = threadIdx.x & 63;
    const int khalf = __builtin_amdgcn_readfirstlane((int)(threadIdx.x >> 6));
    const int bid = blockIdx.x;                      // 0..767
    const bool isL1 = bid >= 384;
    if (isL1 ? (s < 1) : (s >= TT)) return;          // block-uniform
    const int tile = isL1 ? bid - 384 : bid;         // 0..383

    if (isL1)
        phaseA_impl<512>(tile, khalf, lane, fe, wsp, w_ih1, w_hh1, kb1, p1,
                         FZ1H, FZ1L, FS1H, FS1L, FB1H, FB1L, SWT1H, SWT1L);
    else
        phaseA_impl<128>(tile, khalf, lane, fe, wsp, w_ih0, w_hh0, kb0, p0,
                         FZ0H, FZ0L, FS0H, FS0L, FB0H, FB0L, SWT0H, SWT0L);
}

// phase B: cell updates + feature gen; 256 blocks (1/CU) grid-stride.
__global__ __launch_bounds__(256) void phaseB_kernel(
    ushort* __restrict__ fe, const float* __restrict__ p0, const float* __restrict__ p1,
    float* __restrict__ c0T, float* __restrict__ h1T, float* __restrict__ c1T,
    const float* __restrict__ b_ih0, const float* __restrict__ b_hh0,
    const float* __restrict__ b_ih1, const float* __restrict__ b_hh1,
    const float* __restrict__ x, int s)
{
    for (int u = blockIdx.x * 256 + threadIdx.x; u < 73728; u += 65536) {
        if (u < 32768) {
            if (s >= TT) continue;
            const int o = u & 511, b = u >> 9;
            auto P = [&](int rw) {
                return p0[(size_t)b * 6144 + rw] + p0[393216 + (size_t)b * 6144 + rw];
            };
            float si = P(o)        + b_ih0[o]        + b_hh0[o];
            float sf = P(512 + o)  + b_ih0[512 + o]  + b_hh0[512 + o];
            float sO = P(1024 + o) + b_ih0[1024 + o] + b_hh0[1024 + o];
            float sk = P(1536 + o);
#pragma unroll
            for (int rr = 0; rr < 8; ++rr) sk += P(2048 + rr * 512 + o);
            float ig = sigmoidf_(si), fg = sigmoidf_(sf), og = sigmoidf_(sO);
            float c = fg * c0T[(size_t)b * 512 + o] + ig * sk;
            c0T[(size_t)b * 512 + o] = c;
            float z = og * tanhf(c);
            write_featsT(z, fe, FZ1H, FZ1L, FS1H, FS1L, FB1H, FB1L,
                         65536, (size_t)b * 1024 + o);            // L1 input, t=s
            write_featsT(z, fe, FZ0H, FZ0L, FS0H, FS0L, FB0H, FB0L,
                         40960, (size_t)b * 640 + 128 + o);       // L0 hidden, t=s+1
        } else if (u < 65536) {
            if (s < 1) continue;
            const int v = u - 32768, o = v & 511, b = v >> 9;
            auto P = [&](int rw) {
                return p1[(size_t)b * 6144 + rw] + p1[393216 + (size_t)b * 6144 + rw];
            };
            float si = P(o)        + b_ih1[o]        + b_hh1[o];
            float sf = P(512 + o)  + b_ih1[512 + o]  + b_hh1[512 + o];
            float sO = P(1024 + o) + b_ih1[1024 + o] + b_hh1[1024 + o];
            float sk = P(1536 + o);
#pragma unroll
            for (int rr = 0; rr < 8; ++rr) sk += P(2048 + rr * 512 + o);
            float ig = sigmoidf_(si), fg = sigmoidf_(sf), og = sigmoidf_(sO);
            float c = fg * c1T[(size_t)b * 512 + o] + ig * sk;
            c1T[(size_t)b * 512 + o] = c;
            float z = og * tanhf(c);
            h1T[(size_t)b * 512 + o] = z;
            write_featsT(z, fe, FZ1H, FZ1L, FS1H, FS1L, FB1H, FB1L,
                         65536, (size_t)b * 1024 + 512 + o);      // L1 hidden, t=s
        } else {
            if (s + 1 >= TT) continue;
            const int v = u - 65536, k = v & 127, b = v >> 7;
            float z = x[((size_t)b * TT + (s + 1)) * 128 + k];
            write_featsT(z, fe, FZ0H, FZ0L, FS0H, FS0L, FB0H, FB0L,
                         40960, (size_t)b * 640 + k);             // L0 x, t=s+1
        }
    }
}

// out[b][jo] = h1T[b] . fc_w[jo] + fc_b[jo]  (fp32 out)
__global__ __launch_bounds__(256) void final_fc(
    const float* __restrict__ h1T, const float* __restrict__ fc_w,
    const float* __restrict__ fc_b, float* __restrict__ out)
{
    const int gid = blockIdx.x * 256 + threadIdx.x;   // 8192
    const int b = gid & 63, jo = gid >> 6;
    float a = fc_b[jo];
    const float* hr = h1T + (size_t)b * 512;
    const float* wr = fc_w + (size_t)jo * 512;
    for (int o = 0; o < 512; o += 4) {
        float4 h4 = *(const float4*)(hr + o);
        float4 w4 = *(const float4*)(wr + o);
        a = fmaf(h4.x, w4.x, a); a = fmaf(h4.y, w4.y, a);
        a = fmaf(h4.z, w4.z, a); a = fmaf(h4.w, w4.w, a);
    }
    out[(size_t)b * 128 + jo] = a;
}

} // namespace

extern "C" void kernel_launch(void* const* d_in, const int* in_sizes, int n_in,
                              void* d_out, int out_size, void* d_ws, size_t ws_size,
                              hipStream_t stream) {
    (void)out_size;
    float* out = (float*)d_out;

    static const int EXP_SIZES[15] = {
        64 * 256 * 128, 1536 * 128, 1536 * 512, 1536, 1536,
        512 * 640, 512 * 640 * 8,
        1536 * 512, 1536 * 512, 1536, 1536,
        512 * 1024, 512 * 1024 * 8,
        128 * 512, 128
    };
    if (n_in != 15) { sentinel_kernel<<<32, 256, 0, stream>>>(out, 111.0f); return; }
    for (int i = 0; i < 15; ++i)
        if (in_sizes[i] != EXP_SIZES[i]) {
            sentinel_kernel<<<32, 256, 0, stream>>>(out, 200.0f * (i + 1)); return;
        }
    if (ws_size < WS_NEED) { sentinel_kernel<<<32, 256, 0, stream>>>(out, 7777.0f); return; }

    const float* x     = (const float*)d_in[0];
    const float* w_ih0 = (const float*)d_in[1];
    const float* w_hh0 = (const float*)d_in[2];
    const float* b_ih0 = (const float*)d_in[3];
    const float* b_hh0 = (const float*)d_in[4];
    const float* kb0   = (const float*)d_in[5];
    const float* ksp0  = (const float*)d_in[6];
    const float* w_ih1 = (const float*)d_in[7];
    const float* w_hh1 = (const float*)d_in[8];
    const float* b_ih1 = (const float*)d_in[9];
    const float* b_hh1 = (const float*)d_in[10];
    const float* kb1   = (const float*)d_in[11];
    const float* ksp1  = (const float*)d_in[12];
    const float* fc_w  = (const float*)d_in[13];
    const float* fc_b  = (const float*)d_in[14];

    float* ws = (float*)d_ws;
    float* st = ws + S_ST;
    float* p0 = ws + S_P0;
    float* p1 = ws + S_P1;
    ushort* wsp = (ushort*)(ws + S_WSP);
    ushort* fe  = (ushort*)(ws + S_FEAT);

    prologue_kernel<<<672, 256, 0, stream>>>(x, st, fe);
    split_swT<640><<<1280, 256, 0, stream>>>(ksp0, wsp + SWT0H, wsp + SWT0L);
    split_swT<1024><<<2048, 256, 0, stream>>>(ksp1, wsp + SWT1H, wsp + SWT1L);

    for (int s = 0; s <= TT; ++s) {
        phaseA_kernel<<<768, 128, 0, stream>>>(fe, wsp, p0, p1,
            w_ih0, w_hh0, kb0, w_ih1, w_hh1, kb1, s);
        phaseB_kernel<<<256, 256, 0, stream>>>(fe, p0, p1, st, st + 32768,
            st + 65536, b_ih0, b_hh0, b_ih1, b_hh1, x, s);
    }

    final_fc<<<32, 256, 0, stream>>>(st + 32768, fc_w, fc_b, out);
}

// Round 17
// 8919.766 us; speedup vs baseline: 1.3141x; 1.0446x over previous
//
#include <hip/hip_runtime.h>
#include <math.h>
#include <stdint.h>

namespace {

typedef __attribute__((ext_vector_type(8))) short short8v;   // 8 bf16 = 4 VGPR
typedef __attribute__((ext_vector_type(4))) float f32x4;

constexpr int TT = 256;

// ---- ws float offsets (total 9,551,872 floats = 38.2 MB, proven) ----
constexpr size_t OFF_ST   = 0;         // c0T,h1T,c1T  [3][64][512]
constexpr size_t OFF_P0   = 98304;     // [2][64][6144]
constexpr size_t OFF_P1   = 884736;    // [2][64][6144]
constexpr size_t OFF_SWT0 = 1671168;   // [8][512][640]  fp32
constexpr size_t OFF_SWT1 = 4292608;   // [8][512][1024] fp32
constexpr size_t OFF_FEAT = 8486912;   // ushort area (1,064,960 floats)
constexpr size_t WS_NEED  = 9551872ull * 4;

// ---- ushort offsets within FEAT ----
constexpr size_t FZ0H = 0,       FZ0L = 40960,  FS0H = 81920,  FS0L = 122880;
constexpr size_t FB0H = 163840,  FB0L = 491520;                 // planes 64*640
constexpr size_t L1F  = 819200;
constexpr size_t FZ1H = L1F,          FZ1L = L1F + 65536;
constexpr size_t FS1H = L1F + 131072, FS1L = L1F + 196608;
constexpr size_t FB1H = L1F + 262144, FB1L = L1F + 786432;      // planes 64*1024

__device__ __forceinline__ float sigmoidf_(float v) { return 1.0f / (1.0f + expf(-v)); }

__device__ __forceinline__ ushort bf16h(float v) {          // RNE f32 -> bf16 bits
    uint32_t u = __float_as_uint(v);
    return (ushort)((u + 0x7fffu + ((u >> 16) & 1u)) >> 16);
}
__device__ __forceinline__ float bf16f(ushort h) { return __uint_as_float(((uint32_t)h) << 16); }
__device__ __forceinline__ void put2(ushort* hi, ushort* lo, size_t idx, float v) {
    ushort h = bf16h(v); hi[idx] = h; lo[idx] = bf16h(v - bf16f(h));
}

// Cox-de Boor, GRID_SIZE=5, ORDER=3 (verified rounds 7-16)
__device__ __forceinline__ void bspline8(float x, float* out) {
    const float KG[12] = {-2.2f,-1.8f,-1.4f,-1.0f,-0.6f,-0.2f,
                           0.2f, 0.6f, 1.0f, 1.4f, 1.8f, 2.2f};
    float b[11];
#pragma unroll
    for (int i = 0; i < 11; ++i)
        b[i] = (x >= KG[i] && x < KG[i + 1]) ? 1.0f : 0.0f;
#pragma unroll
    for (int p = 1; p <= 3; ++p) {
#pragma unroll
        for (int i = 0; i + p < 11; ++i) {
            float l = (x - KG[i])         * (1.0f / (KG[i + p] - KG[i]));
            float r = (KG[i + p + 1] - x) * (1.0f / (KG[i + p + 1] - KG[i + 1]));
            b[i] = l * b[i] + r * b[i + 1];
        }
    }
#pragma unroll
    for (int i = 0; i < 8; ++i) out[i] = b[i];
}

// z, silu(z), 8 spline bases -> hi/lo bf16, transposed [b][k] layout
__device__ __forceinline__ void write_featsT(float z, ushort* fe,
        size_t zh, size_t zl, size_t sh, size_t sl, size_t bh, size_t bl,
        size_t pstride, size_t idx)
{
    put2(fe + zh, fe + zl, idx, z);
    put2(fe + sh, fe + sl, idx, z / (1.0f + expf(-z)));
    float bs[8];
    bspline8(z, bs);
#pragma unroll
    for (int r = 0; r < 8; ++r)
        put2(fe + bh + (size_t)r * pstride, fe + bl + (size_t)r * pstride, idx, bs[r]);
}

__global__ __launch_bounds__(256) void sentinel_kernel(float* out, float v) {
    int i = blockIdx.x * 256 + threadIdx.x;
    if (i < 8192) out[i] = v;
}

// states zero + t=0 x-features + zero-state hidden features for both layers
__global__ __launch_bounds__(256) void prologue_kernel(
    const float* __restrict__ x, float* __restrict__ ws)
{
    ushort* fe = (ushort*)(ws + OFF_FEAT);
    const int g = blockIdx.x * 256 + threadIdx.x;    // 672*256 = 172032
    if (g < 98304) {
        ws[OFF_ST + g] = 0.0f;                       // c0T,h1T,c1T
    } else if (g < 106496) {                         // t=0 x feats (k<128)
        const int i = g - 98304, k = i & 127, b = i >> 7;
        write_featsT(x[((size_t)b * TT) * 128 + k], fe,
                     FZ0H, FZ0L, FS0H, FS0L, FB0H, FB0L, 40960, (size_t)b * 640 + k);
    } else if (g < 139264) {                         // L0 hidden feats h0(-1)=0
        const int i = g - 106496, o = i & 511, b = i >> 9;
        write_featsT(0.0f, fe, FZ0H, FZ0L, FS0H, FS0L, FB0H, FB0L,
                     40960, (size_t)b * 640 + 128 + o);
    } else {                                         // L1 hidden feats h1(-1)=0
        const int i = g - 139264, o = i & 511, b = i >> 9;
        write_featsT(0.0f, fe, FZ1H, FZ1L, FS1H, FS1L, FB1H, FB1L,
                     65536, (size_t)b * 1024 + 512 + o);
    }
}

// sw [512][W][8] -> swT [8][512][W] fp32 (A-fragment wants k contiguous)
template <int W>
__global__ __launch_bounds__(256) void transpose_sw(const float* __restrict__ sw,
                                                    float* __restrict__ swT) {
    const int i = blockIdx.x * 256 + threadIdx.x;   // over 512*W
    float v[8];
#pragma unroll
    for (int r = 0; r < 8; ++r) v[r] = sw[(size_t)i * 8 + r];
#pragma unroll
    for (int r = 0; r < 8; ++r) swT[(size_t)r * 512 * W + i] = v[r];
}

// phase A: MFMA GEMM, fp32-equivalent via split-bf16 (3 products).
// EXACT round-12 structure; ONLY change: blockIdx -> task swizzle so XCD
// (bid%8, assumed dispatch round-robin) owns a CONTIGUOUS 96-task range ->
// per-XCD weight working set ~4-6 MB (L0 gates fit 4MB L2 exactly) instead
// of ~37MB scattered. Bijective permutation -> bit-identical numerics.
__global__ __launch_bounds__(128) void phaseA_kernel(
    float* __restrict__ ws,
    const float* __restrict__ w_ih0, const float* __restrict__ w_hh0,
    const float* __restrict__ kb0,
    const float* __restrict__ w_ih1, const float* __restrict__ w_hh1,
    const float* __restrict__ kb1, int s)
{
    const int lane = threadIdx.x & 63;
    const int wv   = __builtin_amdgcn_readfirstlane((int)(threadIdx.x >> 6));
    const int bid  = blockIdx.x;                     // 0..767
    const int btask = ((bid & 7) * 96) + (bid >> 3); // XCD-contiguous tasks
    const int wid  = btask * 2 + wv;                 // 0..1535
    const bool isL1 = wid >= 768;
    if (isL1 ? (s < 1) : (s >= TT)) return;
    const int r    = isL1 ? wid - 768 : wid;
    const int tile = r >> 1, khalf = r & 1;
    const int IN = isL1 ? 512 : 128, W = IN + 512, KC = W >> 1, NSL = KC >> 5;

    const ushort* fe = (const ushort*)(ws + OFF_FEAT);
    float* p = ws + (isL1 ? OFF_P1 : OFF_P0) + (size_t)khalf * 393216;

    const int m = lane & 15, kg = lane >> 4;
    const int o0 = tile * 16;
    const float* wrow_a; const float* wrow_b = nullptr;
    const ushort *fhi, *flo;
    if (tile < 96) {                                  // gate rows (z features)
        wrow_a = (isL1 ? w_ih1 : w_ih0) + (size_t)(o0 + m) * IN;
        wrow_b = (isL1 ? w_hh1 : w_hh0) + (size_t)(o0 + m) * 512;
        fhi = fe + (isL1 ? FZ1H : FZ0H);  flo = fe + (isL1 ? FZ1L : FZ0L);
    } else if (tile < 128) {                          // base rows (silu features)
        wrow_a = (isL1 ? kb1 : kb0) + (size_t)((tile - 96) * 16 + m) * W;
        fhi = fe + (isL1 ? FS1H : FS0H);  flo = fe + (isL1 ? FS1L : FS0L);
    } else {                                          // spline rows (basis features)
        const int rr = (tile - 128) >> 5, op = ((tile - 128) & 31) * 16 + m;
        wrow_a = ws + (isL1 ? OFF_SWT1 : OFF_SWT0) + ((size_t)rr * 512 + op) * W;
        fhi = fe + (isL1 ? FB1H : FB0H) + (size_t)rr * 64 * W;
        flo = fe + (isL1 ? FB1L : FB0L) + (size_t)rr * 64 * W;
    }

    f32x4 acc[4] = {{0,0,0,0},{0,0,0,0},{0,0,0,0},{0,0,0,0}};
    const int kbase = khalf * KC;

    for (int sl = 0; sl < NSL; ++sl) {
        const int k0 = kbase + sl * 32;
        const int kk = k0 + kg * 8;
        const float* wp = (tile < 96 && k0 >= IN) ? (wrow_b + (kk - IN)) : (wrow_a + kk);
        float4 wa = *(const float4*)wp;
        float4 wb4 = *(const float4*)(wp + 4);
        const float wvv[8] = {wa.x, wa.y, wa.z, wa.w, wb4.x, wb4.y, wb4.z, wb4.w};
        short8v whi, wlo;
#pragma unroll
        for (int j = 0; j < 8; ++j) {
            ushort h = bf16h(wvv[j]);
            whi[j] = (short)h;
            wlo[j] = (short)bf16h(wvv[j] - bf16f(h));
        }
#pragma unroll
        for (int bt = 0; bt < 4; ++bt) {
            const size_t fidx = (size_t)(bt * 16 + m) * W + kk;
            short8v bh = *(const short8v*)(fhi + fidx);
            short8v bl = *(const short8v*)(flo + fidx);
            acc[bt] = __builtin_amdgcn_mfma_f32_16x16x32_bf16(whi, bh, acc[bt], 0, 0, 0);
            acc[bt] = __builtin_amdgcn_mfma_f32_16x16x32_bf16(whi, bl, acc[bt], 0, 0, 0);
            acc[bt] = __builtin_amdgcn_mfma_f32_16x16x32_bf16(wlo, bh, acc[bt], 0, 0, 0);
        }
    }

#pragma unroll
    for (int bt = 0; bt < 4; ++bt) {
        float* dst = p + (size_t)(bt * 16 + m) * 6144 + o0 + kg * 4;
        *(float4*)dst = (float4){acc[bt][0], acc[bt][1], acc[bt][2], acc[bt][3]};
    }
}

// phase B: cell updates (sum 2 K-halves) + feature generation; o-fast mapping.
// EXACT round-12 version (288 blocks, direct mapping).
__global__ __launch_bounds__(256) void phaseB_kernel(
    float* __restrict__ ws,
    const float* __restrict__ b_ih0, const float* __restrict__ b_hh0,
    const float* __restrict__ b_ih1, const float* __restrict__ b_hh1,
    const float* __restrict__ x, int s)
{
    ushort* fe = (ushort*)(ws + OFF_FEAT);
    float* c0T = ws + OFF_ST;
    float* h1T = c0T + 32768;
    float* c1T = h1T + 32768;
    const float* p0 = ws + OFF_P0;
    const float* p1 = ws + OFF_P1;

    const int u = blockIdx.x * 256 + threadIdx.x;    // 288*256 = 73728
    if (u < 32768) {
        if (s >= TT) return;
        const int o = u & 511, b = u >> 9;
        auto P = [&](int rw) {
            return p0[(size_t)b * 6144 + rw] + p0[393216 + (size_t)b * 6144 + rw];
        };
        float si = P(o)        + b_ih0[o]        + b_hh0[o];
        float sf = P(512 + o)  + b_ih0[512 + o]  + b_hh0[512 + o];
        float sO = P(1024 + o) + b_ih0[1024 + o] + b_hh0[1024 + o];
        float sk = P(1536 + o);
#pragma unroll
        for (int rr = 0; rr < 8; ++rr) sk += P(2048 + rr * 512 + o);
        float ig = sigmoidf_(si), fg = sigmoidf_(sf), og = sigmoidf_(sO);
        float c = fg * c0T[(size_t)b * 512 + o] + ig * sk;
        c0T[(size_t)b * 512 + o] = c;
        float z = og * tanhf(c);
        write_featsT(z, fe, FZ1H, FZ1L, FS1H, FS1L, FB1H, FB1L,
                     65536, (size_t)b * 1024 + o);            // L1 input, t=s
        write_featsT(z, fe, FZ0H, FZ0L, FS0H, FS0L, FB0H, FB0L,
                     40960, (size_t)b * 640 + 128 + o);       // L0 hidden, t=s+1
    } else if (u < 65536) {
        if (s < 1) return;
        const int v = u - 32768, o = v & 511, b = v >> 9;
        auto P = [&](int rw) {
            return p1[(size_t)b * 6144 + rw] + p1[393216 + (size_t)b * 6144 + rw];
        };
        float si = P(o)        + b_ih1[o]        + b_hh1[o];
        float sf = P(512 + o)  + b_ih1[512 + o]  + b_hh1[512 + o];
        float sO = P(1024 + o) + b_ih1[1024 + o] + b_hh1[1024 + o];
        float sk = P(1536 + o);
#pragma unroll
        for (int rr = 0; rr < 8; ++rr) sk += P(2048 + rr * 512 + o);
        float ig = sigmoidf_(si), fg = sigmoidf_(sf), og = sigmoidf_(sO);
        float c = fg * c1T[(size_t)b * 512 + o] + ig * sk;
        c1T[(size_t)b * 512 + o] = c;
        float z = og * tanhf(c);
        h1T[(size_t)b * 512 + o] = z;
        write_featsT(z, fe, FZ1H, FZ1L, FS1H, FS1L, FB1H, FB1L,
                     65536, (size_t)b * 1024 + 512 + o);      // L1 hidden, t=s
    } else {
        if (s + 1 >= TT) return;
        const int v = u - 65536, k = v & 127, b = v >> 7;
        float z = x[((size_t)b * TT + (s + 1)) * 128 + k];
        write_featsT(z, fe, FZ0H, FZ0L, FS0H, FS0L, FB0H, FB0L,
                     40960, (size_t)b * 640 + k);             // L0 x, t=s+1
    }
}

// out[b][jo] = h1T[b] . fc_w[jo] + fc_b[jo]  (fp32 out)
__global__ __launch_bounds__(256) void final_fc(
    const float* __restrict__ h1T, const float* __restrict__ fc_w,
    const float* __restrict__ fc_b, float* __restrict__ out)
{
    const int gid = blockIdx.x * 256 + threadIdx.x;   // 8192
    const int b = gid & 63, jo = gid >> 6;
    float a = fc_b[jo];
    const float* hr = h1T + (size_t)b * 512;
    const float* wr = fc_w + (size_t)jo * 512;
    for (int o = 0; o < 512; o += 4) {
        float4 h4 = *(const float4*)(hr + o);
        float4 w4 = *(const float4*)(wr + o);
        a = fmaf(h4.x, w4.x, a); a = fmaf(h4.y, w4.y, a);
        a = fmaf(h4.z, w4.z, a); a = fmaf(h4.w, w4.w, a);
    }
    out[(size_t)b * 128 + jo] = a;
}

} // namespace

extern "C" void kernel_launch(void* const* d_in, const int* in_sizes, int n_in,
                              void* d_out, int out_size, void* d_ws, size_t ws_size,
                              hipStream_t stream) {
    (void)out_size;
    float* out = (float*)d_out;

    static const int EXP_SIZES[15] = {
        64 * 256 * 128, 1536 * 128, 1536 * 512, 1536, 1536,
        512 * 640, 512 * 640 * 8,
        1536 * 512, 1536 * 512, 1536, 1536,
        512 * 1024, 512 * 1024 * 8,
        128 * 512, 128
    };
    if (n_in != 15) { sentinel_kernel<<<32, 256, 0, stream>>>(out, 111.0f); return; }
    for (int i = 0; i < 15; ++i)
        if (in_sizes[i] != EXP_SIZES[i]) {
            sentinel_kernel<<<32, 256, 0, stream>>>(out, 200.0f * (i + 1)); return;
        }
    if (ws_size < WS_NEED) { sentinel_kernel<<<32, 256, 0, stream>>>(out, 7777.0f); return; }

    const float* x     = (const float*)d_in[0];
    const float* w_ih0 = (const float*)d_in[1];
    const float* w_hh0 = (const float*)d_in[2];
    const float* b_ih0 = (const float*)d_in[3];
    const float* b_hh0 = (const float*)d_in[4];
    const float* kb0   = (const float*)d_in[5];
    const float* ksp0  = (const float*)d_in[6];
    const float* w_ih1 = (const float*)d_in[7];
    const float* w_hh1 = (const float*)d_in[8];
    const float* b_ih1 = (const float*)d_in[9];
    const float* b_hh1 = (const float*)d_in[10];
    const float* kb1   = (const float*)d_in[11];
    const float* ksp1  = (const float*)d_in[12];
    const float* fc_w  = (const float*)d_in[13];
    const float* fc_b  = (const float*)d_in[14];

    float* ws = (float*)d_ws;

    prologue_kernel<<<672, 256, 0, stream>>>(x, ws);
    transpose_sw<640><<<1280, 256, 0, stream>>>(ksp0, ws + OFF_SWT0);
    transpose_sw<1024><<<2048, 256, 0, stream>>>(ksp1, ws + OFF_SWT1);

    for (int s = 0; s <= TT; ++s) {
        phaseA_kernel<<<768, 128, 0, stream>>>(
            ws, w_ih0, w_hh0, kb0, w_ih1, w_hh1, kb1, s);
        phaseB_kernel<<<288, 256, 0, stream>>>(
            ws, b_ih0, b_hh0, b_ih1, b_hh1, x, s);
    }

    final_fc<<<32, 256, 0, stream>>>(ws + OFF_ST + 32768, fc_w, fc_b, out);
}

// Round 18
// 8318.045 us; speedup vs baseline: 1.4091x; 1.0723x over previous
//
#include <hip/hip_runtime.h>
#include <math.h>
#include <stdint.h>

namespace {

typedef __attribute__((ext_vector_type(8))) short short8v;   // 8 bf16 = 4 VGPR
typedef __attribute__((ext_vector_type(4))) float f32x4;

constexpr int TT = 256;

// ---- ws float offsets (total 9,551,872 floats = 38.2 MB, proven) ----
constexpr size_t OFF_ST   = 0;         // c0T,h1T,c1T  [3][64][512]
constexpr size_t OFF_P0   = 98304;     // [2][64][6144]
constexpr size_t OFF_P1   = 884736;    // [2][64][6144]
constexpr size_t OFF_SWT0 = 1671168;   // [8][512][640]  fp32
constexpr size_t OFF_SWT1 = 4292608;   // [8][512][1024] fp32
constexpr size_t OFF_FEAT = 8486912;   // ushort area (1,064,960 floats)
constexpr size_t WS_NEED  = 9551872ull * 4;

// ---- ushort offsets within FEAT ----
constexpr size_t FZ0H = 0,       FZ0L = 40960,  FS0H = 81920,  FS0L = 122880;
constexpr size_t FB0H = 163840,  FB0L = 491520;                 // planes 64*640
constexpr size_t L1F  = 819200;
constexpr size_t FZ1H = L1F,          FZ1L = L1F + 65536;
constexpr size_t FS1H = L1F + 131072, FS1L = L1F + 196608;
constexpr size_t FB1H = L1F + 262144, FB1L = L1F + 786432;      // planes 64*1024

__device__ __forceinline__ float sigmoidf_(float v) { return 1.0f / (1.0f + expf(-v)); }

__device__ __forceinline__ ushort bf16h(float v) {          // RNE f32 -> bf16 bits
    uint32_t u = __float_as_uint(v);
    return (ushort)((u + 0x7fffu + ((u >> 16) & 1u)) >> 16);
}
__device__ __forceinline__ float bf16f(ushort h) { return __uint_as_float(((uint32_t)h) << 16); }
__device__ __forceinline__ void put2(ushort* hi, ushort* lo, size_t idx, float v) {
    ushort h = bf16h(v); hi[idx] = h; lo[idx] = bf16h(v - bf16f(h));
}

// Cox-de Boor, GRID_SIZE=5, ORDER=3 (verified rounds 7-17)
__device__ __forceinline__ void bspline8(float x, float* out) {
    const float KG[12] = {-2.2f,-1.8f,-1.4f,-1.0f,-0.6f,-0.2f,
                           0.2f, 0.6f, 1.0f, 1.4f, 1.8f, 2.2f};
    float b[11];
#pragma unroll
    for (int i = 0; i < 11; ++i)
        b[i] = (x >= KG[i] && x < KG[i + 1]) ? 1.0f : 0.0f;
#pragma unroll
    for (int p = 1; p <= 3; ++p) {
#pragma unroll
        for (int i = 0; i + p < 11; ++i) {
            float l = (x - KG[i])         * (1.0f / (KG[i + p] - KG[i]));
            float r = (KG[i + p + 1] - x) * (1.0f / (KG[i + p + 1] - KG[i + 1]));
            b[i] = l * b[i] + r * b[i + 1];
        }
    }
#pragma unroll
    for (int i = 0; i < 8; ++i) out[i] = b[i];
}

// z, silu(z), 8 spline bases -> hi/lo bf16, transposed [b][k] layout
__device__ __forceinline__ void write_featsT(float z, ushort* fe,
        size_t zh, size_t zl, size_t sh, size_t sl, size_t bh, size_t bl,
        size_t pstride, size_t idx)
{
    put2(fe + zh, fe + zl, idx, z);
    put2(fe + sh, fe + sl, idx, z / (1.0f + expf(-z)));
    float bs[8];
    bspline8(z, bs);
#pragma unroll
    for (int r = 0; r < 8; ++r)
        put2(fe + bh + (size_t)r * pstride, fe + bl + (size_t)r * pstride, idx, bs[r]);
}

__global__ __launch_bounds__(256) void sentinel_kernel(float* out, float v) {
    int i = blockIdx.x * 256 + threadIdx.x;
    if (i < 8192) out[i] = v;
}

// states zero + t=0 x-features + zero-state hidden features for both layers
__global__ __launch_bounds__(256) void prologue_kernel(
    const float* __restrict__ x, float* __restrict__ ws)
{
    ushort* fe = (ushort*)(ws + OFF_FEAT);
    const int g = blockIdx.x * 256 + threadIdx.x;    // 672*256 = 172032
    if (g < 98304) {
        ws[OFF_ST + g] = 0.0f;                       // c0T,h1T,c1T
    } else if (g < 106496) {                         // t=0 x feats (k<128)
        const int i = g - 98304, k = i & 127, b = i >> 7;
        write_featsT(x[((size_t)b * TT) * 128 + k], fe,
                     FZ0H, FZ0L, FS0H, FS0L, FB0H, FB0L, 40960, (size_t)b * 640 + k);
    } else if (g < 139264) {                         // L0 hidden feats h0(-1)=0
        const int i = g - 106496, o = i & 511, b = i >> 9;
        write_featsT(0.0f, fe, FZ0H, FZ0L, FS0H, FS0L, FB0H, FB0L,
                     40960, (size_t)b * 640 + 128 + o);
    } else {                                         // L1 hidden feats h1(-1)=0
        const int i = g - 139264, o = i & 511, b = i >> 9;
        write_featsT(0.0f, fe, FZ1H, FZ1L, FS1H, FS1L, FB1H, FB1L,
                     65536, (size_t)b * 1024 + 512 + o);
    }
}

// sw [512][W][8] -> swT [8][512][W] fp32 (A-fragment wants k contiguous)
template <int W>
__global__ __launch_bounds__(256) void transpose_sw(const float* __restrict__ sw,
                                                    float* __restrict__ swT) {
    const int i = blockIdx.x * 256 + threadIdx.x;   // over 512*W
    float v[8];
#pragma unroll
    for (int r = 0; r < 8; ++r) v[r] = sw[(size_t)i * 8 + r];
#pragma unroll
    for (int r = 0; r < 8; ++r) swT[(size_t)r * 512 * W + i] = v[r];
}

// phase A: MFMA GEMM, fp32-equivalent via split-bf16 (3 products).
// EXACT round-12 task map; ONE change: manual depth-1 software pipeline —
// slice sl+1's weight+feature loads are issued BEFORE slice sl's
// split-VALU + MFMA chain, so ~200cy of compute covers the load latency.
// Arithmetic order identical -> absmax must stay bit-identical.
__global__ __launch_bounds__(128) void phaseA_kernel(
    float* __restrict__ ws,
    const float* __restrict__ w_ih0, const float* __restrict__ w_hh0,
    const float* __restrict__ kb0,
    const float* __restrict__ w_ih1, const float* __restrict__ w_hh1,
    const float* __restrict__ kb1, int s)
{
    const int lane = threadIdx.x & 63;
    const int wv   = __builtin_amdgcn_readfirstlane((int)(threadIdx.x >> 6));
    const int wid  = blockIdx.x * 2 + wv;            // 0..1535
    const bool isL1 = wid >= 768;
    if (isL1 ? (s < 1) : (s >= TT)) return;
    const int r    = isL1 ? wid - 768 : wid;
    const int tile = r >> 1, khalf = r & 1;
    const int IN = isL1 ? 512 : 128, W = IN + 512, KC = W >> 1, NSL = KC >> 5;

    const ushort* fe = (const ushort*)(ws + OFF_FEAT);
    float* p = ws + (isL1 ? OFF_P1 : OFF_P0) + (size_t)khalf * 393216;

    const int m = lane & 15, kg = lane >> 4;
    const int o0 = tile * 16;
    const float* wrow_a; const float* wrow_b = nullptr;
    const ushort *fhi, *flo;
    if (tile < 96) {                                  // gate rows (z features)
        wrow_a = (isL1 ? w_ih1 : w_ih0) + (size_t)(o0 + m) * IN;
        wrow_b = (isL1 ? w_hh1 : w_hh0) + (size_t)(o0 + m) * 512;
        fhi = fe + (isL1 ? FZ1H : FZ0H);  flo = fe + (isL1 ? FZ1L : FZ0L);
    } else if (tile < 128) {                          // base rows (silu features)
        wrow_a = (isL1 ? kb1 : kb0) + (size_t)((tile - 96) * 16 + m) * W;
        fhi = fe + (isL1 ? FS1H : FS0H);  flo = fe + (isL1 ? FS1L : FS0L);
    } else {                                          // spline rows (basis features)
        const int rr = (tile - 128) >> 5, op = ((tile - 128) & 31) * 16 + m;
        wrow_a = ws + (isL1 ? OFF_SWT1 : OFF_SWT0) + ((size_t)rr * 512 + op) * W;
        fhi = fe + (isL1 ? FB1H : FB0H) + (size_t)rr * 64 * W;
        flo = fe + (isL1 ? FB1L : FB0L) + (size_t)rr * 64 * W;
    }

    f32x4 acc[4] = {{0,0,0,0},{0,0,0,0},{0,0,0,0},{0,0,0,0}};
    const int kbase = khalf * KC;

    auto wptr = [&](int sl) -> const float* {
        const int k0 = kbase + sl * 32;
        const int kk = k0 + kg * 8;
        return (tile < 96 && k0 >= IN) ? (wrow_b + (kk - IN)) : (wrow_a + kk);
    };

    // prefetch slice 0
    float4 cwa, cwb;
    short8v cbh[4], cbl[4];
    {
        const float* wp = wptr(0);
        cwa = *(const float4*)wp;
        cwb = *(const float4*)(wp + 4);
        const int kk = kbase + kg * 8;
#pragma unroll
        for (int bt = 0; bt < 4; ++bt) {
            const size_t fidx = (size_t)(bt * 16 + m) * W + kk;
            cbh[bt] = *(const short8v*)(fhi + fidx);
            cbl[bt] = *(const short8v*)(flo + fidx);
        }
    }

    for (int sl = 0; sl < NSL; ++sl) {
        float4 nwa, nwb;
        short8v nbh[4], nbl[4];
        const bool hasNext = (sl + 1 < NSL);
        if (hasNext) {                               // issue next-slice loads FIRST
            const float* np = wptr(sl + 1);
            nwa = *(const float4*)np;
            nwb = *(const float4*)(np + 4);
            const int kkn = kbase + (sl + 1) * 32 + kg * 8;
#pragma unroll
            for (int bt = 0; bt < 4; ++bt) {
                const size_t fidx = (size_t)(bt * 16 + m) * W + kkn;
                nbh[bt] = *(const short8v*)(fhi + fidx);
                nbl[bt] = *(const short8v*)(flo + fidx);
            }
        }

        // split current weights (same op order as r12)
        const float wvv[8] = {cwa.x, cwa.y, cwa.z, cwa.w, cwb.x, cwb.y, cwb.z, cwb.w};
        short8v whi, wlo;
#pragma unroll
        for (int j = 0; j < 8; ++j) {
            ushort h = bf16h(wvv[j]);
            whi[j] = (short)h;
            wlo[j] = (short)bf16h(wvv[j] - bf16f(h));
        }
#pragma unroll
        for (int bt = 0; bt < 4; ++bt) {
            acc[bt] = __builtin_amdgcn_mfma_f32_16x16x32_bf16(whi, cbh[bt], acc[bt], 0, 0, 0);
            acc[bt] = __builtin_amdgcn_mfma_f32_16x16x32_bf16(whi, cbl[bt], acc[bt], 0, 0, 0);
            acc[bt] = __builtin_amdgcn_mfma_f32_16x16x32_bf16(wlo, cbh[bt], acc[bt], 0, 0, 0);
        }

        if (hasNext) {
            cwa = nwa; cwb = nwb;
#pragma unroll
            for (int bt = 0; bt < 4; ++bt) { cbh[bt] = nbh[bt]; cbl[bt] = nbl[bt]; }
        }
    }

#pragma unroll
    for (int bt = 0; bt < 4; ++bt) {
        float* dst = p + (size_t)(bt * 16 + m) * 6144 + o0 + kg * 4;
        *(float4*)dst = (float4){acc[bt][0], acc[bt][1], acc[bt][2], acc[bt][3]};
    }
}

// phase B: cell updates (sum 2 K-halves) + feature generation; o-fast mapping.
// EXACT round-12 version (288 blocks, direct mapping).
__global__ __launch_bounds__(256) void phaseB_kernel(
    float* __restrict__ ws,
    const float* __restrict__ b_ih0, const float* __restrict__ b_hh0,
    const float* __restrict__ b_ih1, const float* __restrict__ b_hh1,
    const float* __restrict__ x, int s)
{
    ushort* fe = (ushort*)(ws + OFF_FEAT);
    float* c0T = ws + OFF_ST;
    float* h1T = c0T + 32768;
    float* c1T = h1T + 32768;
    const float* p0 = ws + OFF_P0;
    const float* p1 = ws + OFF_P1;

    const int u = blockIdx.x * 256 + threadIdx.x;    // 288*256 = 73728
    if (u < 32768) {
        if (s >= TT) return;
        const int o = u & 511, b = u >> 9;
        auto P = [&](int rw) {
            return p0[(size_t)b * 6144 + rw] + p0[393216 + (size_t)b * 6144 + rw];
        };
        float si = P(o)        + b_ih0[o]        + b_hh0[o];
        float sf = P(512 + o)  + b_ih0[512 + o]  + b_hh0[512 + o];
        float sO = P(1024 + o) + b_ih0[1024 + o] + b_hh0[1024 + o];
        float sk = P(1536 + o);
#pragma unroll
        for (int rr = 0; rr < 8; ++rr) sk += P(2048 + rr * 512 + o);
        float ig = sigmoidf_(si), fg = sigmoidf_(sf), og = sigmoidf_(sO);
        float c = fg * c0T[(size_t)b * 512 + o] + ig * sk;
        c0T[(size_t)b * 512 + o] = c;
        float z = og * tanhf(c);
        write_featsT(z, fe, FZ1H, FZ1L, FS1H, FS1L, FB1H, FB1L,
                     65536, (size_t)b * 1024 + o);            // L1 input, t=s
        write_featsT(z, fe, FZ0H, FZ0L, FS0H, FS0L, FB0H, FB0L,
                     40960, (size_t)b * 640 + 128 + o);       // L0 hidden, t=s+1
    } else if (u < 65536) {
        if (s < 1) return;
        const int v = u - 32768, o = v & 511, b = v >> 9;
        auto P = [&](int rw) {
            return p1[(size_t)b * 6144 + rw] + p1[393216 + (size_t)b * 6144 + rw];
        };
        float si = P(o)        + b_ih1[o]        + b_hh1[o];
        float sf = P(512 + o)  + b_ih1[512 + o]  + b_hh1[512 + o];
        float sO = P(1024 + o) + b_ih1[1024 + o] + b_hh1[1024 + o];
        float sk = P(1536 + o);
#pragma unroll
        for (int rr = 0; rr < 8; ++rr) sk += P(2048 + rr * 512 + o);
        float ig = sigmoidf_(si), fg = sigmoidf_(sf), og = sigmoidf_(sO);
        float c = fg * c1T[(size_t)b * 512 + o] + ig * sk;
        c1T[(size_t)b * 512 + o] = c;
        float z = og * tanhf(c);
        h1T[(size_t)b * 512 + o] = z;
        write_featsT(z, fe, FZ1H, FZ1L, FS1H, FS1L, FB1H, FB1L,
                     65536, (size_t)b * 1024 + 512 + o);      // L1 hidden, t=s
    } else {
        if (s + 1 >= TT) return;
        const int v = u - 65536, k = v & 127, b = v >> 7;
        float z = x[((size_t)b * TT + (s + 1)) * 128 + k];
        write_featsT(z, fe, FZ0H, FZ0L, FS0H, FS0L, FB0H, FB0L,
                     40960, (size_t)b * 640 + k);             // L0 x, t=s+1
    }
}

// out[b][jo] = h1T[b] . fc_w[jo] + fc_b[jo]  (fp32 out)
__global__ __launch_bounds__(256) void final_fc(
    const float* __restrict__ h1T, const float* __restrict__ fc_w,
    const float* __restrict__ fc_b, float* __restrict__ out)
{
    const int gid = blockIdx.x * 256 + threadIdx.x;   // 8192
    const int b = gid & 63, jo = gid >> 6;
    float a = fc_b[jo];
    const float* hr = h1T + (size_t)b * 512;
    const float* wr = fc_w + (size_t)jo * 512;
    for (int o = 0; o < 512; o += 4) {
        float4 h4 = *(const float4*)(hr + o);
        float4 w4 = *(const float4*)(wr + o);
        a = fmaf(h4.x, w4.x, a); a = fmaf(h4.y, w4.y, a);
        a = fmaf(h4.z, w4.z, a); a = fmaf(h4.w, w4.w, a);
    }
    out[(size_t)b * 128 + jo] = a;
}

} // namespace

extern "C" void kernel_launch(void* const* d_in, const int* in_sizes, int n_in,
                              void* d_out, int out_size, void* d_ws, size_t ws_size,
                              hipStream_t stream) {
    (void)out_size;
    float* out = (float*)d_out;

    static const int EXP_SIZES[15] = {
        64 * 256 * 128, 1536 * 128, 1536 * 512, 1536, 1536,
        512 * 640, 512 * 640 * 8,
        1536 * 512, 1536 * 512, 1536, 1536,
        512 * 1024, 512 * 1024 * 8,
        128 * 512, 128
    };
    if (n_in != 15) { sentinel_kernel<<<32, 256, 0, stream>>>(out, 111.0f); return; }
    for (int i = 0; i < 15; ++i)
        if (in_sizes[i] != EXP_SIZES[i]) {
            sentinel_kernel<<<32, 256, 0, stream>>>(out, 200.0f * (i + 1)); return;
        }
    if (ws_size < WS_NEED) { sentinel_kernel<<<32, 256, 0, stream>>>(out, 7777.0f); return; }

    const float* x     = (const float*)d_in[0];
    const float* w_ih0 = (const float*)d_in[1];
    const float* w_hh0 = (const float*)d_in[2];
    const float* b_ih0 = (const float*)d_in[3];
    const float* b_hh0 = (const float*)d_in[4];
    const float* kb0   = (const float*)d_in[5];
    const float* ksp0  = (const float*)d_in[6];
    const float* w_ih1 = (const float*)d_in[7];
    const float* w_hh1 = (const float*)d_in[8];
    const float* b_ih1 = (const float*)d_in[9];
    const float* b_hh1 = (const float*)d_in[10];
    const float* kb1   = (const float*)d_in[11];
    const float* ksp1  = (const float*)d_in[12];
    const float* fc_w  = (const float*)d_in[13];
    const float* fc_b  = (const float*)d_in[14];

    float* ws = (float*)d_ws;

    prologue_kernel<<<672, 256, 0, stream>>>(x, ws);
    transpose_sw<640><<<1280, 256, 0, stream>>>(ksp0, ws + OFF_SWT0);
    transpose_sw<1024><<<2048, 256, 0, stream>>>(ksp1, ws + OFF_SWT1);

    for (int s = 0; s <= TT; ++s) {
        phaseA_kernel<<<768, 128, 0, stream>>>(
            ws, w_ih0, w_hh0, kb0, w_ih1, w_hh1, kb1, s);
        phaseB_kernel<<<288, 256, 0, stream>>>(
            ws, b_ih0, b_hh0, b_ih1, b_hh1, x, s);
    }

    final_fc<<<32, 256, 0, stream>>>(ws + OFF_ST + 32768, fc_w, fc_b, out);
}

// Round 19
// 6096.648 us; speedup vs baseline: 1.9225x; 1.3644x over previous
//
#include <hip/hip_runtime.h>
#include <math.h>
#include <stdint.h>

namespace {

typedef __attribute__((ext_vector_type(8))) short short8v;   // 8 bf16 = 4 VGPR
typedef __attribute__((ext_vector_type(4))) float f32x4;

constexpr int TT = 256;

// ---- ws float offsets (total 12,959,744 floats = 51.84 MB) ----
constexpr size_t OFF_ST = 0;          // c0T,h1T,c1T [3][64][512]
constexpr size_t OFF_P0 = 98304;      // [2][64][6144]
constexpr size_t OFF_P1 = 884736;     // [2][64][6144]
constexpr size_t OFF_WF = 1671168;    // 20,447,232 ushorts: frag weights hi|lo
constexpr size_t OFF_FF = 11894784;   // 2,129,920 ushorts: frag features hi|lo
constexpr size_t WS_NEED = 12959744ull * 4;

constexpr size_t WFLO = 10223616;     // ushort offset of weight lo plane
constexpr size_t FFLO = 1064960;      // ushort offset of feature lo plane
constexpr size_t FLB1 = 409600;       // feature base of layer 1 (ushorts)

__device__ __forceinline__ float sigmoidf_(float v) { return 1.0f / (1.0f + expf(-v)); }

__device__ __forceinline__ ushort bf16h(float v) {          // RNE f32 -> bf16 bits
    uint32_t u = __float_as_uint(v);
    return (ushort)((u + 0x7fffu + ((u >> 16) & 1u)) >> 16);
}
__device__ __forceinline__ float bf16f(ushort h) { return __uint_as_float(((uint32_t)h) << 16); }

// Cox-de Boor, GRID_SIZE=5, ORDER=3 (verified rounds 7-18)
__device__ __forceinline__ void bspline8(float x, float* out) {
    const float KG[12] = {-2.2f,-1.8f,-1.4f,-1.0f,-0.6f,-0.2f,
                           0.2f, 0.6f, 1.0f, 1.4f, 1.8f, 2.2f};
    float b[11];
#pragma unroll
    for (int i = 0; i < 11; ++i)
        b[i] = (x >= KG[i] && x < KG[i + 1]) ? 1.0f : 0.0f;
#pragma unroll
    for (int p = 1; p <= 3; ++p) {
#pragma unroll
        for (int i = 0; i + p < 11; ++i) {
            float l = (x - KG[i])         * (1.0f / (KG[i + p] - KG[i]));
            float r = (KG[i + p + 1] - x) * (1.0f / (KG[i + p + 1] - KG[i + 1]));
            b[i] = l * b[i] + r * b[i + 1];
        }
    }
#pragma unroll
    for (int i = 0; i < 8; ++i) out[i] = b[i];
}

// Write z, silu, 8 bases for (layer l, feature k, batch b) in FRAGMENT order:
// plane p (0=z,1=silu,2+r=basis r), address
//   LB(l) + ((p*2+kh)*NSL + sl)*2048 + (bt*64 + lane)*8 + j
// where kh=k>=KC, kr=k-kh*KC, sl=kr>>5, kg=(kr>>3)&3, j=kr&7,
//       lane=(b&15)+16*kg, bt=b>>4.
__device__ __forceinline__ void putFeat(int l, int k, int b, float z,
                                        ushort* __restrict__ fe)
{
    const int NSL = l ? 16 : 10, KC = l ? 512 : 320;
    const int kh = (k >= KC) ? 1 : 0, kr = k - kh * KC;
    const int sl = kr >> 5, kg = (kr >> 3) & 3, j = kr & 7;
    const size_t cell = (size_t)((b >> 4) * 64 + (b & 15) + 16 * kg) * 8 + j;
    const size_t LB = l ? FLB1 : 0;
    const size_t slb = ((size_t)kh * NSL + sl) * 2048 + cell;   // plane p adds p*2*NSL*2048
    const size_t pstep = (size_t)2 * NSL * 2048;

    auto putp = [&](int p, float v) {
        size_t idx = LB + (size_t)p * pstep + slb;
        ushort h = bf16h(v);
        fe[idx] = h;
        fe[FFLO + idx] = bf16h(v - bf16f(h));
    };
    putp(0, z);
    putp(1, z / (1.0f + expf(-z)));
    float bs[8];
    bspline8(z, bs);
#pragma unroll
    for (int r = 0; r < 8; ++r) putp(2 + r, bs[r]);
}

__global__ __launch_bounds__(256) void sentinel_kernel(float* out, float v) {
    int i = blockIdx.x * 256 + threadIdx.x;
    if (i < 8192) out[i] = v;
}

// Build fragment-ordered split weights. Thread = (sliceblock s, lane).
// s<7680: L0 (wid=s/10, sl=s%10); else L1 (wid=768+(s-7680)/16, sl=(s-7680)%16).
// wid = l*768 + kh*384 + tile.
__global__ __launch_bounds__(256) void wbuild_kernel(
    ushort* __restrict__ wf,
    const float* __restrict__ w_ih0, const float* __restrict__ w_hh0,
    const float* __restrict__ kb0, const float* __restrict__ ksp0,
    const float* __restrict__ w_ih1, const float* __restrict__ w_hh1,
    const float* __restrict__ kb1, const float* __restrict__ ksp1)
{
    const int gid = blockIdx.x * 256 + threadIdx.x;   // 4992*256 = 19968*64
    const int s = gid >> 6, lane = gid & 63;
    int wid, sl;
    if (s < 7680) { wid = s / 10; sl = s % 10; }
    else          { wid = 768 + (s - 7680) / 16; sl = (s - 7680) % 16; }
    const int l = wid >= 768 ? 1 : 0;
    const int r2 = wid - l * 768;
    const int kh = r2 >= 384 ? 1 : 0;
    const int tile = r2 - kh * 384;
    const int IN = l ? 512 : 128, W = IN + 512, KC = W >> 1;
    const int m = lane & 15, kg = lane >> 4;
    const int k0 = kh * KC + sl * 32;
    const int kk = k0 + kg * 8;
    const int o0 = tile * 16;

    const float* w_ih = l ? w_ih1 : w_ih0;
    const float* w_hh = l ? w_hh1 : w_hh0;
    const float* kb   = l ? kb1 : kb0;
    const float* ksp  = l ? ksp1 : ksp0;

    float vv[8];
    if (tile < 96) {
        const int row = o0 + m;
#pragma unroll
        for (int j = 0; j < 8; ++j) {
            const int k = kk + j;
            vv[j] = (k0 < IN) ? w_ih[(size_t)row * IN + k]
                              : w_hh[(size_t)row * 512 + (k - IN)];
        }
    } else if (tile < 128) {
        const int row = (tile - 96) * 16 + m;
#pragma unroll
        for (int j = 0; j < 8; ++j) vv[j] = kb[(size_t)row * W + kk + j];
    } else {
        const int rr = (tile - 128) >> 5, op = ((tile - 128) & 31) * 16 + m;
#pragma unroll
        for (int j = 0; j < 8; ++j)
            vv[j] = ksp[((size_t)op * W + kk + j) * 8 + rr];
    }
    const size_t base = (size_t)s * 512 + (size_t)lane * 8;
#pragma unroll
    for (int j = 0; j < 8; ++j) {
        ushort h = bf16h(vv[j]);
        wf[base + j] = h;
        wf[WFLO + base + j] = bf16h(vv[j] - bf16f(h));
    }
}

// states zero + t=0 x-features + zero-state hidden features for both layers
__global__ __launch_bounds__(256) void prologue_kernel(
    const float* __restrict__ x, float* __restrict__ ws)
{
    ushort* fe = (ushort*)(ws + OFF_FF);
    const int g = blockIdx.x * 256 + threadIdx.x;    // 672*256 = 172032
    if (g < 98304) {
        ws[OFF_ST + g] = 0.0f;                       // c0T,h1T,c1T
    } else if (g < 106496) {                         // t=0 x feats (k<128)
        const int i = g - 98304, k = i & 127, b = i >> 7;
        putFeat(0, k, b, x[((size_t)b * TT) * 128 + k], fe);
    } else if (g < 139264) {                         // L0 hidden feats h0(-1)=0
        const int i = g - 106496, o = i & 511, b = i >> 9;
        putFeat(0, 128 + o, b, 0.0f, fe);
    } else {                                         // L1 hidden feats h1(-1)=0
        const int i = g - 139264, o = i & 511, b = i >> 9;
        putFeat(1, 512 + o, b, 0.0f, fe);
    }
}

// phase A: MFMA GEMM, split-bf16 (3 products), fragment-ordered memory.
// 384 blocks x 256 thr; block = 4 adjacent tiles (same ftype-plane) x 1 khalf.
// Per slice: 8KB feature block staged in LDS (shared by 4 waves, traffic /4);
// weights read as contiguous 512B hi + 512B lo fragments.
__global__ __launch_bounds__(256) void phaseA_kernel(
    float* __restrict__ ws, int s)
{
    __shared__ short8v sfh[256], sfl[256];           // 8 KB

    const int t = threadIdx.x, lane = t & 63;
    const int wv = __builtin_amdgcn_readfirstlane(t >> 6);
    const int bid = blockIdx.x;                      // 0..383
    const int l  = bid >= 192 ? 1 : 0;
    if (l ? (s < 1) : (s >= TT)) return;             // block-uniform
    const int r3 = bid - l * 192;
    const int kh = r3 >= 96 ? 1 : 0;
    const int grp = r3 - kh * 96;                    // 0..95
    const int tile = grp * 4 + wv;
    const int NSL = l ? 16 : 10;
    // plane p uniform across the 4 tiles of the group
    const int p = (grp < 24) ? 0 : (grp < 32) ? 1 : (2 + ((grp - 32) >> 3));

    const ushort* wf = (const ushort*)(ws + OFF_WF);
    const ushort* fe = (const ushort*)(ws + OFF_FF);
    float* pout = ws + (l ? OFF_P1 : OFF_P0) + (size_t)kh * 393216;

    const int wid = l * 768 + kh * 384 + tile;
    const size_t sbase = l ? (7680 + (size_t)(wid - 768) * 16) : (size_t)wid * 10;
    const size_t fbase = (l ? FLB1 : 0) +
                         ((size_t)(p * 2 + kh) * NSL) * 2048;   // + sl*2048

    const int m = lane & 15, kg = lane >> 4;
    const int o0 = tile * 16;

    f32x4 acc[4] = {{0,0,0,0},{0,0,0,0},{0,0,0,0},{0,0,0,0}};

    // prefetch slice 0 features (16B hi + 16B lo per thread)
    short8v rh = *(const short8v*)(fe + fbase + (size_t)t * 8);
    short8v rl = *(const short8v*)(fe + FFLO + fbase + (size_t)t * 8);

    for (int sl = 0; sl < NSL; ++sl) {
        __syncthreads();                             // prior slice reads done
        sfh[t] = rh; sfl[t] = rl;
        __syncthreads();                             // staged
        if (sl + 1 < NSL) {                          // prefetch next (hides under MFMA)
            const size_t nb = fbase + (size_t)(sl + 1) * 2048 + (size_t)t * 8;
            rh = *(const short8v*)(fe + nb);
            rl = *(const short8v*)(fe + FFLO + nb);
        }
        const size_t wb = (sbase + sl) * 512 + (size_t)lane * 8;
        short8v whi = *(const short8v*)(wf + wb);
        short8v wlo = *(const short8v*)(wf + WFLO + wb);
#pragma unroll
        for (int bt = 0; bt < 4; ++bt) {
            short8v bh = sfh[bt * 64 + lane];
            short8v bl = sfl[bt * 64 + lane];
            acc[bt] = __builtin_amdgcn_mfma_f32_16x16x32_bf16(whi, bh, acc[bt], 0, 0, 0);
            acc[bt] = __builtin_amdgcn_mfma_f32_16x16x32_bf16(whi, bl, acc[bt], 0, 0, 0);
            acc[bt] = __builtin_amdgcn_mfma_f32_16x16x32_bf16(wlo, bh, acc[bt], 0, 0, 0);
        }
    }

#pragma unroll
    for (int bt = 0; bt < 4; ++bt) {
        float* dst = pout + (size_t)(bt * 16 + m) * 6144 + o0 + kg * 4;
        *(float4*)dst = (float4){acc[bt][0], acc[bt][1], acc[bt][2], acc[bt][3]};
    }
}

// phase B: cell updates (sum 2 K-halves) + feature generation (fragment order).
__global__ __launch_bounds__(256) void phaseB_kernel(
    float* __restrict__ ws,
    const float* __restrict__ b_ih0, const float* __restrict__ b_hh0,
    const float* __restrict__ b_ih1, const float* __restrict__ b_hh1,
    const float* __restrict__ x, int s)
{
    ushort* fe = (ushort*)(ws + OFF_FF);
    float* c0T = ws + OFF_ST;
    float* h1T = c0T + 32768;
    float* c1T = h1T + 32768;
    const float* p0 = ws + OFF_P0;
    const float* p1 = ws + OFF_P1;

    const int u = blockIdx.x * 256 + threadIdx.x;    // 288*256 = 73728
    if (u < 32768) {
        if (s >= TT) return;
        const int o = u & 511, b = u >> 9;
        auto P = [&](int rw) {
            return p0[(size_t)b * 6144 + rw] + p0[393216 + (size_t)b * 6144 + rw];
        };
        float si = P(o)        + b_ih0[o]        + b_hh0[o];
        float sf = P(512 + o)  + b_ih0[512 + o]  + b_hh0[512 + o];
        float sO = P(1024 + o) + b_ih0[1024 + o] + b_hh0[1024 + o];
        float sk = P(1536 + o);
#pragma unroll
        for (int rr = 0; rr < 8; ++rr) sk += P(2048 + rr * 512 + o);
        float ig = sigmoidf_(si), fg = sigmoidf_(sf), og = sigmoidf_(sO);
        float c = fg * c0T[(size_t)b * 512 + o] + ig * sk;
        c0T[(size_t)b * 512 + o] = c;
        float z = og * tanhf(c);
        putFeat(1, o, b, z, fe);                     // L1 input, t=s
        putFeat(0, 128 + o, b, z, fe);               // L0 hidden, t=s+1
    } else if (u < 65536) {
        if (s < 1) return;
        const int v = u - 32768, o = v & 511, b = v >> 9;
        auto P = [&](int rw) {
            return p1[(size_t)b * 6144 + rw] + p1[393216 + (size_t)b * 6144 + rw];
        };
        float si = P(o)        + b_ih1[o]        + b_hh1[o];
        float sf = P(512 + o)  + b_ih1[512 + o]  + b_hh1[512 + o];
        float sO = P(1024 + o) + b_ih1[1024 + o] + b_hh1[1024 + o];
        float sk = P(1536 + o);
#pragma unroll
        for (int rr = 0; rr < 8; ++rr) sk += P(2048 + rr * 512 + o);
        float ig = sigmoidf_(si), fg = sigmoidf_(sf), og = sigmoidf_(sO);
        float c = fg * c1T[(size_t)b * 512 + o] + ig * sk;
        c1T[(size_t)b * 512 + o] = c;
        float z = og * tanhf(c);
        h1T[(size_t)b * 512 + o] = z;
        putFeat(1, 512 + o, b, z, fe);               // L1 hidden, t=s
    } else {
        if (s + 1 >= TT) return;
        const int v = u - 65536, k = v & 127, b = v >> 7;
        putFeat(0, k, b, x[((size_t)b * TT + (s + 1)) * 128 + k], fe);  // L0 x, t=s+1
    }
}

// out[b][jo] = h1T[b] . fc_w[jo] + fc_b[jo]  (fp32 out)
__global__ __launch_bounds__(256) void final_fc(
    const float* __restrict__ h1T, const float* __restrict__ fc_w,
    const float* __restrict__ fc_b, float* __restrict__ out)
{
    const int gid = blockIdx.x * 256 + threadIdx.x;   // 8192
    const int b = gid & 63, jo = gid >> 6;
    float a = fc_b[jo];
    const float* hr = h1T + (size_t)b * 512;
    const float* wr = fc_w + (size_t)jo * 512;
    for (int o = 0; o < 512; o += 4) {
        float4 h4 = *(const float4*)(hr + o);
        float4 w4 = *(const float4*)(wr + o);
        a = fmaf(h4.x, w4.x, a); a = fmaf(h4.y, w4.y, a);
        a = fmaf(h4.z, w4.z, a); a = fmaf(h4.w, w4.w, a);
    }
    out[(size_t)b * 128 + jo] = a;
}

} // namespace

extern "C" void kernel_launch(void* const* d_in, const int* in_sizes, int n_in,
                              void* d_out, int out_size, void* d_ws, size_t ws_size,
                              hipStream_t stream) {
    (void)out_size;
    float* out = (float*)d_out;

    static const int EXP_SIZES[15] = {
        64 * 256 * 128, 1536 * 128, 1536 * 512, 1536, 1536,
        512 * 640, 512 * 640 * 8,
        1536 * 512, 1536 * 512, 1536, 1536,
        512 * 1024, 512 * 1024 * 8,
        128 * 512, 128
    };
    if (n_in != 15) { sentinel_kernel<<<32, 256, 0, stream>>>(out, 111.0f); return; }
    for (int i = 0; i < 15; ++i)
        if (in_sizes[i] != EXP_SIZES[i]) {
            sentinel_kernel<<<32, 256, 0, stream>>>(out, 200.0f * (i + 1)); return;
        }
    if (ws_size < WS_NEED) { sentinel_kernel<<<32, 256, 0, stream>>>(out, 7777.0f); return; }

    const float* x     = (const float*)d_in[0];
    const float* w_ih0 = (const float*)d_in[1];
    const float* w_hh0 = (const float*)d_in[2];
    const float* b_ih0 = (const float*)d_in[3];
    const float* b_hh0 = (const float*)d_in[4];
    const float* kb0   = (const float*)d_in[5];
    const float* ksp0  = (const float*)d_in[6];
    const float* w_ih1 = (const float*)d_in[7];
    const float* w_hh1 = (const float*)d_in[8];
    const float* b_ih1 = (const float*)d_in[9];
    const float* b_hh1 = (const float*)d_in[10];
    const float* kb1   = (const float*)d_in[11];
    const float* ksp1  = (const float*)d_in[12];
    const float* fc_w  = (const float*)d_in[13];
    const float* fc_b  = (const float*)d_in[14];

    float* ws = (float*)d_ws;

    prologue_kernel<<<672, 256, 0, stream>>>(x, ws);
    wbuild_kernel<<<4992, 256, 0, stream>>>((ushort*)(ws + OFF_WF),
        w_ih0, w_hh0, kb0, ksp0, w_ih1, w_hh1, kb1, ksp1);

    for (int s = 0; s <= TT; ++s) {
        phaseA_kernel<<<384, 256, 0, stream>>>(ws, s);
        phaseB_kernel<<<288, 256, 0, stream>>>(
            ws, b_ih0, b_hh0, b_ih1, b_hh1, x, s);
    }

    final_fc<<<32, 256, 0, stream>>>(ws + OFF_ST + 32768, fc_w, fc_b, out);
}

// Round 20
// 5669.784 us; speedup vs baseline: 2.0673x; 1.0753x over previous
//
#include <hip/hip_runtime.h>
#include <math.h>
#include <stdint.h>

namespace {

typedef __attribute__((ext_vector_type(8))) short short8v;   // 8 bf16 = 4 VGPR
typedef __attribute__((ext_vector_type(4))) float f32x4;

constexpr int TT = 256;

// ---- ws float offsets (total 12,959,744 floats = 51.84 MB) ----
constexpr size_t OFF_ST = 0;          // c0T,h1T,c1T [3][64][512]
constexpr size_t OFF_P0 = 98304;      // [2][64][6144]
constexpr size_t OFF_P1 = 884736;     // [2][64][6144]
constexpr size_t OFF_WF = 1671168;    // 20,447,232 ushorts: frag weights hi|lo
constexpr size_t OFF_FF = 11894784;   // 2,129,920 ushorts: frag features hi|lo
constexpr size_t WS_NEED = 12959744ull * 4;

constexpr size_t WFLO = 10223616;     // ushort offset of weight lo plane
constexpr size_t FFLO = 1064960;      // ushort offset of feature lo plane
constexpr size_t FLB1 = 409600;       // feature base of layer 1 (ushorts)

__device__ __forceinline__ float sigmoidf_(float v) { return 1.0f / (1.0f + expf(-v)); }

__device__ __forceinline__ ushort bf16h(float v) {          // RNE f32 -> bf16 bits
    uint32_t u = __float_as_uint(v);
    return (ushort)((u + 0x7fffu + ((u >> 16) & 1u)) >> 16);
}
__device__ __forceinline__ float bf16f(ushort h) { return __uint_as_float(((uint32_t)h) << 16); }

// Cox-de Boor, GRID_SIZE=5, ORDER=3 (verified rounds 7-19)
__device__ __forceinline__ void bspline8(float x, float* out) {
    const float KG[12] = {-2.2f,-1.8f,-1.4f,-1.0f,-0.6f,-0.2f,
                           0.2f, 0.6f, 1.0f, 1.4f, 1.8f, 2.2f};
    float b[11];
#pragma unroll
    for (int i = 0; i < 11; ++i)
        b[i] = (x >= KG[i] && x < KG[i + 1]) ? 1.0f : 0.0f;
#pragma unroll
    for (int p = 1; p <= 3; ++p) {
#pragma unroll
        for (int i = 0; i + p < 11; ++i) {
            float l = (x - KG[i])         * (1.0f / (KG[i + p] - KG[i]));
            float r = (KG[i + p + 1] - x) * (1.0f / (KG[i + p + 1] - KG[i + 1]));
            b[i] = l * b[i] + r * b[i + 1];
        }
    }
#pragma unroll
    for (int i = 0; i < 8; ++i) out[i] = b[i];
}

// Write z, silu, 8 bases for (layer l, feature k, batch b) in FRAGMENT order.
__device__ __forceinline__ void putFeat(int l, int k, int b, float z,
                                        ushort* __restrict__ fe)
{
    const int NSL = l ? 16 : 10, KC = l ? 512 : 320;
    const int kh = (k >= KC) ? 1 : 0, kr = k - kh * KC;
    const int sl = kr >> 5, kg = (kr >> 3) & 3, j = kr & 7;
    const size_t cell = (size_t)((b >> 4) * 64 + (b & 15) + 16 * kg) * 8 + j;
    const size_t LB = l ? FLB1 : 0;
    const size_t slb = ((size_t)kh * NSL + sl) * 2048 + cell;
    const size_t pstep = (size_t)2 * NSL * 2048;

    auto putp = [&](int p, float v) {
        size_t idx = LB + (size_t)p * pstep + slb;
        ushort h = bf16h(v);
        fe[idx] = h;
        fe[FFLO + idx] = bf16h(v - bf16f(h));
    };
    putp(0, z);
    putp(1, z / (1.0f + expf(-z)));
    float bs[8];
    bspline8(z, bs);
#pragma unroll
    for (int r = 0; r < 8; ++r) putp(2 + r, bs[r]);
}

__global__ __launch_bounds__(256) void sentinel_kernel(float* out, float v) {
    int i = blockIdx.x * 256 + threadIdx.x;
    if (i < 8192) out[i] = v;
}

// Build fragment-ordered split weights (identical to round 19).
__global__ __launch_bounds__(256) void wbuild_kernel(
    ushort* __restrict__ wf,
    const float* __restrict__ w_ih0, const float* __restrict__ w_hh0,
    const float* __restrict__ kb0, const float* __restrict__ ksp0,
    const float* __restrict__ w_ih1, const float* __restrict__ w_hh1,
    const float* __restrict__ kb1, const float* __restrict__ ksp1)
{
    const int gid = blockIdx.x * 256 + threadIdx.x;   // 4992*256 = 19968*64
    const int s = gid >> 6, lane = gid & 63;
    int wid, sl;
    if (s < 7680) { wid = s / 10; sl = s % 10; }
    else          { wid = 768 + (s - 7680) / 16; sl = (s - 7680) % 16; }
    const int l = wid >= 768 ? 1 : 0;
    const int r2 = wid - l * 768;
    const int kh = r2 >= 384 ? 1 : 0;
    const int tile = r2 - kh * 384;
    const int IN = l ? 512 : 128, W = IN + 512, KC = W >> 1;
    const int m = lane & 15, kg = lane >> 4;
    const int k0 = kh * KC + sl * 32;
    const int kk = k0 + kg * 8;
    const int o0 = tile * 16;

    const float* w_ih = l ? w_ih1 : w_ih0;
    const float* w_hh = l ? w_hh1 : w_hh0;
    const float* kb   = l ? kb1 : kb0;
    const float* ksp  = l ? ksp1 : ksp0;

    float vv[8];
    if (tile < 96) {
        const int row = o0 + m;
#pragma unroll
        for (int j = 0; j < 8; ++j) {
            const int k = kk + j;
            vv[j] = (k0 < IN) ? w_ih[(size_t)row * IN + k]
                              : w_hh[(size_t)row * 512 + (k - IN)];
        }
    } else if (tile < 128) {
        const int row = (tile - 96) * 16 + m;
#pragma unroll
        for (int j = 0; j < 8; ++j) vv[j] = kb[(size_t)row * W + kk + j];
    } else {
        const int rr = (tile - 128) >> 5, op = ((tile - 128) & 31) * 16 + m;
#pragma unroll
        for (int j = 0; j < 8; ++j)
            vv[j] = ksp[((size_t)op * W + kk + j) * 8 + rr];
    }
    const size_t base = (size_t)s * 512 + (size_t)lane * 8;
#pragma unroll
    for (int j = 0; j < 8; ++j) {
        ushort h = bf16h(vv[j]);
        wf[base + j] = h;
        wf[WFLO + base + j] = bf16h(vv[j] - bf16f(h));
    }
}

// states zero + t=0 x-features + zero-state hidden features for both layers
__global__ __launch_bounds__(256) void prologue_kernel(
    const float* __restrict__ x, float* __restrict__ ws)
{
    ushort* fe = (ushort*)(ws + OFF_FF);
    const int g = blockIdx.x * 256 + threadIdx.x;    // 672*256 = 172032
    if (g < 98304) {
        ws[OFF_ST + g] = 0.0f;                       // c0T,h1T,c1T
    } else if (g < 106496) {                         // t=0 x feats (k<128)
        const int i = g - 98304, k = i & 127, b = i >> 7;
        putFeat(0, k, b, x[((size_t)b * TT) * 128 + k], fe);
    } else if (g < 139264) {                         // L0 hidden feats h0(-1)=0
        const int i = g - 106496, o = i & 511, b = i >> 9;
        putFeat(0, 128 + o, b, 0.0f, fe);
    } else {                                         // L1 hidden feats h1(-1)=0
        const int i = g - 139264, o = i & 511, b = i >> 9;
        putFeat(1, 512 + o, b, 0.0f, fe);
    }
}

// phase A: MFMA GEMM, split-bf16 (3 products), fragment-ordered memory.
// r19 structure + DOUBLE-BUFFERED LDS with issue-early/write-late:
// per slice: issue next loads -> MFMA (hides latency) -> LDS write (buf^1)
// -> ONE barrier. Halves barrier count, moves load wait off critical path.
__global__ __launch_bounds__(256) void phaseA_kernel(
    float* __restrict__ ws, int s)
{
    __shared__ short8v sfh[2][256], sfl[2][256];     // 16 KB

    const int t = threadIdx.x, lane = t & 63;
    const int wv = __builtin_amdgcn_readfirstlane(t >> 6);
    const int bid = blockIdx.x;                      // 0..383
    const int l  = bid >= 192 ? 1 : 0;
    if (l ? (s < 1) : (s >= TT)) return;             // block-uniform
    const int r3 = bid - l * 192;
    const int kh = r3 >= 96 ? 1 : 0;
    const int grp = r3 - kh * 96;                    // 0..95
    const int tile = grp * 4 + wv;
    const int NSL = l ? 16 : 10;
    const int p = (grp < 24) ? 0 : (grp < 32) ? 1 : (2 + ((grp - 32) >> 3));

    const ushort* wf = (const ushort*)(ws + OFF_WF);
    const ushort* fe = (const ushort*)(ws + OFF_FF);
    float* pout = ws + (l ? OFF_P1 : OFF_P0) + (size_t)kh * 393216;

    const int wid = l * 768 + kh * 384 + tile;
    const size_t sbase = l ? (7680 + (size_t)(wid - 768) * 16) : (size_t)wid * 10;
    const size_t fbase = (l ? FLB1 : 0) +
                         ((size_t)(p * 2 + kh) * NSL) * 2048;

    const int m = lane & 15, kg = lane >> 4;
    const int o0 = tile * 16;

    f32x4 acc[4] = {{0,0,0,0},{0,0,0,0},{0,0,0,0},{0,0,0,0}};

    // ---- prologue: slice 0 features staged, slice 0 weights in regs ----
    {
        short8v rh = *(const short8v*)(fe + fbase + (size_t)t * 8);
        short8v rl = *(const short8v*)(fe + FFLO + fbase + (size_t)t * 8);
        sfh[0][t] = rh; sfl[0][t] = rl;
    }
    short8v cwh = *(const short8v*)(wf + sbase * 512 + (size_t)lane * 8);
    short8v cwl = *(const short8v*)(wf + WFLO + sbase * 512 + (size_t)lane * 8);
    __syncthreads();

    int cur = 0;
    for (int sl = 0; sl < NSL; ++sl) {
        const bool hasNext = (sl + 1 < NSL);
        short8v nfh, nfl, nwh, nwl;
        if (hasNext) {                               // ISSUE next loads first
            const size_t nb = fbase + (size_t)(sl + 1) * 2048 + (size_t)t * 8;
            nfh = *(const short8v*)(fe + nb);
            nfl = *(const short8v*)(fe + FFLO + nb);
            const size_t wb = (sbase + sl + 1) * 512 + (size_t)lane * 8;
            nwh = *(const short8v*)(wf + wb);
            nwl = *(const short8v*)(wf + WFLO + wb);
        }

        // MFMA cluster (loads in flight above)
#pragma unroll
        for (int bt = 0; bt < 4; ++bt) {
            short8v bh = sfh[cur][bt * 64 + lane];
            short8v bl = sfl[cur][bt * 64 + lane];
            acc[bt] = __builtin_amdgcn_mfma_f32_16x16x32_bf16(cwh, bh, acc[bt], 0, 0, 0);
            acc[bt] = __builtin_amdgcn_mfma_f32_16x16x32_bf16(cwh, bl, acc[bt], 0, 0, 0);
            acc[bt] = __builtin_amdgcn_mfma_f32_16x16x32_bf16(cwl, bh, acc[bt], 0, 0, 0);
        }

        if (hasNext) {                               // WRITE late (other buffer)
            sfh[cur ^ 1][t] = nfh;
            sfl[cur ^ 1][t] = nfl;
            cwh = nwh; cwl = nwl;
            __syncthreads();                         // one barrier per slice
            cur ^= 1;
        }
    }

#pragma unroll
    for (int bt = 0; bt < 4; ++bt) {
        float* dst = pout + (size_t)(bt * 16 + m) * 6144 + o0 + kg * 4;
        *(float4*)dst = (float4){acc[bt][0], acc[bt][1], acc[bt][2], acc[bt][3]};
    }
}

// phase B: cell updates (sum 2 K-halves) + feature generation (fragment order).
__global__ __launch_bounds__(256) void phaseB_kernel(
    float* __restrict__ ws,
    const float* __restrict__ b_ih0, const float* __restrict__ b_hh0,
    const float* __restrict__ b_ih1, const float* __restrict__ b_hh1,
    const float* __restrict__ x, int s)
{
    ushort* fe = (ushort*)(ws + OFF_FF);
    float* c0T = ws + OFF_ST;
    float* h1T = c0T + 32768;
    float* c1T = h1T + 32768;
    const float* p0 = ws + OFF_P0;
    const float* p1 = ws + OFF_P1;

    const int u = blockIdx.x * 256 + threadIdx.x;    // 288*256 = 73728
    if (u < 32768) {
        if (s >= TT) return;
        const int o = u & 511, b = u >> 9;
        auto P = [&](int rw) {
            return p0[(size_t)b * 6144 + rw] + p0[393216 + (size_t)b * 6144 + rw];
        };
        float si = P(o)        + b_ih0[o]        + b_hh0[o];
        float sf = P(512 + o)  + b_ih0[512 + o]  + b_hh0[512 + o];
        float sO = P(1024 + o) + b_ih0[1024 + o] + b_hh0[1024 + o];
        float sk = P(1536 + o);
#pragma unroll
        for (int rr = 0; rr < 8; ++rr) sk += P(2048 + rr * 512 + o);
        float ig = sigmoidf_(si), fg = sigmoidf_(sf), og = sigmoidf_(sO);
        float c = fg * c0T[(size_t)b * 512 + o] + ig * sk;
        c0T[(size_t)b * 512 + o] = c;
        float z = og * tanhf(c);
        putFeat(1, o, b, z, fe);                     // L1 input, t=s
        putFeat(0, 128 + o, b, z, fe);               // L0 hidden, t=s+1
    } else if (u < 65536) {
        if (s < 1) return;
        const int v = u - 32768, o = v & 511, b = v >> 9;
        auto P = [&](int rw) {
            return p1[(size_t)b * 6144 + rw] + p1[393216 + (size_t)b * 6144 + rw];
        };
        float si = P(o)        + b_ih1[o]        + b_hh1[o];
        float sf = P(512 + o)  + b_ih1[512 + o]  + b_hh1[512 + o];
        float sO = P(1024 + o) + b_ih1[1024 + o] + b_hh1[1024 + o];
        float sk = P(1536 + o);
#pragma unroll
        for (int rr = 0; rr < 8; ++rr) sk += P(2048 + rr * 512 + o);
        float ig = sigmoidf_(si), fg = sigmoidf_(sf), og = sigmoidf_(sO);
        float c = fg * c1T[(size_t)b * 512 + o] + ig * sk;
        c1T[(size_t)b * 512 + o] = c;
        float z = og * tanhf(c);
        h1T[(size_t)b * 512 + o] = z;
        putFeat(1, 512 + o, b, z, fe);               // L1 hidden, t=s
    } else {
        if (s + 1 >= TT) return;
        const int v = u - 65536, k = v & 127, b = v >> 7;
        putFeat(0, k, b, x[((size_t)b * TT + (s + 1)) * 128 + k], fe);  // L0 x, t=s+1
    }
}

// out[b][jo] = h1T[b] . fc_w[jo] + fc_b[jo]  (fp32 out)
__global__ __launch_bounds__(256) void final_fc(
    const float* __restrict__ h1T, const float* __restrict__ fc_w,
    const float* __restrict__ fc_b, float* __restrict__ out)
{
    const int gid = blockIdx.x * 256 + threadIdx.x;   // 8192
    const int b = gid & 63, jo = gid >> 6;
    float a = fc_b[jo];
    const float* hr = h1T + (size_t)b * 512;
    const float* wr = fc_w + (size_t)jo * 512;
    for (int o = 0; o < 512; o += 4) {
        float4 h4 = *(const float4*)(hr + o);
        float4 w4 = *(const float4*)(wr + o);
        a = fmaf(h4.x, w4.x, a); a = fmaf(h4.y, w4.y, a);
        a = fmaf(h4.z, w4.z, a); a = fmaf(h4.w, w4.w, a);
    }
    out[(size_t)b * 128 + jo] = a;
}

} // namespace

extern "C" void kernel_launch(void* const* d_in, const int* in_sizes, int n_in,
                              void* d_out, int out_size, void* d_ws, size_t ws_size,
                              hipStream_t stream) {
    (void)out_size;
    float* out = (float*)d_out;

    static const int EXP_SIZES[15] = {
        64 * 256 * 128, 1536 * 128, 1536 * 512, 1536, 1536,
        512 * 640, 512 * 640 * 8,
        1536 * 512, 1536 * 512, 1536, 1536,
        512 * 1024, 512 * 1024 * 8,
        128 * 512, 128
    };
    if (n_in != 15) { sentinel_kernel<<<32, 256, 0, stream>>>(out, 111.0f); return; }
    for (int i = 0; i < 15; ++i)
        if (in_sizes[i] != EXP_SIZES[i]) {
            sentinel_kernel<<<32, 256, 0, stream>>>(out, 200.0f * (i + 1)); return;
        }
    if (ws_size < WS_NEED) { sentinel_kernel<<<32, 256, 0, stream>>>(out, 7777.0f); return; }

    const float* x     = (const float*)d_in[0];
    const float* w_ih0 = (const float*)d_in[1];
    const float* w_hh0 = (const float*)d_in[2];
    const float* b_ih0 = (const float*)d_in[3];
    const float* b_hh0 = (const float*)d_in[4];
    const float* kb0   = (const float*)d_in[5];
    const float* ksp0  = (const float*)d_in[6];
    const float* w_ih1 = (const float*)d_in[7];
    const float* w_hh1 = (const float*)d_in[8];
    const float* b_ih1 = (const float*)d_in[9];
    const float* b_hh1 = (const float*)d_in[10];
    const float* kb1   = (const float*)d_in[11];
    const float* ksp1  = (const float*)d_in[12];
    const float* fc_w  = (const float*)d_in[13];
    const float* fc_b  = (const float*)d_in[14];

    float* ws = (float*)d_ws;

    prologue_kernel<<<672, 256, 0, stream>>>(x, ws);
    wbuild_kernel<<<4992, 256, 0, stream>>>((ushort*)(ws + OFF_WF),
        w_ih0, w_hh0, kb0, ksp0, w_ih1, w_hh1, kb1, ksp1);

    for (int s = 0; s <= TT; ++s) {
        phaseA_kernel<<<384, 256, 0, stream>>>(ws, s);
        phaseB_kernel<<<288, 256, 0, stream>>>(
            ws, b_ih0, b_hh0, b_ih1, b_hh1, x, s);
    }

    final_fc<<<32, 256, 0, stream>>>(ws + OFF_ST + 32768, fc_w, fc_b, out);
}